// Round 5
// baseline (1268.513 us; speedup 1.0000x reference)
//
#include <hip/hip_runtime.h>

#define N_NODES 100000
#define N_EDGES 1600000
#define DH 128
#define DOUT 64
#define EPS 1e-6f
#define NBINS 8
#define BINW 12500  // ceil(N_NODES / NBINS)
#define NREP 64     // stats replica buffers

__device__ inline unsigned bfround(float f) {  // f32 -> bf16 bits, round-nearest-even
    unsigned u = __float_as_uint(f);
    return (u + 0x7fffu + ((u >> 16) & 1u)) >> 16;
}
__device__ inline unsigned pack2(float a, float b) { return bfround(a) | (bfround(b) << 16); }

// ---------------- GEMM: Y[nrows, COLS] = f(X)[nrows,128] @ W[128,COLS] + b ----------------
// PN=0: f(X)=Xa.  PN=1: f(X)=relu((Xa-muA)*invA).  PN=2: ...+relu((Xb-muB)*invB)
// OUTBF: write packed bf16, SLICE-MAJOR layout uint[8][N][8] (slice = colpair>>3).
// !OUTBF: write f32 slice-major float[8][N][8] (COLS=64, slice = col>>3).
template <int COLS, int PN, bool OUTBF>
__global__ __launch_bounds__(256) void gemm_kernel(const float* __restrict__ Xa,
                                                   const float* __restrict__ muA,
                                                   const float* __restrict__ invA,
                                                   const float* __restrict__ Xb,
                                                   const float* __restrict__ muB,
                                                   const float* __restrict__ invB,
                                                   const float* __restrict__ W,
                                                   const float* __restrict__ bias,
                                                   void* __restrict__ Yv, int nrows) {
    constexpr int K = 128;
    constexpr int BK = 64;
    constexpr int COLG = COLS / 8;
    constexpr int ROWG = 256 / COLG;
    constexpr int RPT = 64 / ROWG;

    __shared__ float wlds[BK * COLS];
    __shared__ float xlds[64][BK + 1];

    const int tid = threadIdx.x;
    const int row0 = blockIdx.x * 64;

    const float sA = (PN >= 1) ? invA[0] : 0.f;
    const float sB = (PN == 2) ? invB[0] : 0.f;

    const int colg = tid % COLG;
    const int rowg = tid / COLG;
    const int c0 = colg * 8;
    const int r0 = rowg * RPT;

    float acc[RPT][8];
#pragma unroll
    for (int i = 0; i < RPT; ++i)
#pragma unroll
        for (int j = 0; j < 8; ++j) acc[i][j] = 0.f;

    for (int kb = 0; kb < K; kb += BK) {
        constexpr int WVEC = BK * COLS / 4;
        for (int i = tid; i < WVEC; i += 256) {
            int kr = i / (COLS / 4);
            int c4 = i % (COLS / 4);
            reinterpret_cast<float4*>(wlds)[i] =
                reinterpret_cast<const float4*>(W)[(size_t)(kb + kr) * (COLS / 4) + c4];
        }
        for (int i = tid; i < 64 * (BK / 4); i += 256) {
            int r = i / (BK / 4);
            int c4 = i % (BK / 4);
            int col4 = kb / 4 + c4;
            float4 v = make_float4(0.f, 0.f, 0.f, 0.f);
            if (row0 + r < nrows) {
                v = reinterpret_cast<const float4*>(Xa + (size_t)(row0 + r) * K)[col4];
                if constexpr (PN >= 1) {
                    float4 m = reinterpret_cast<const float4*>(muA)[col4];
                    v.x = fmaxf((v.x - m.x) * sA, 0.f);
                    v.y = fmaxf((v.y - m.y) * sA, 0.f);
                    v.z = fmaxf((v.z - m.z) * sA, 0.f);
                    v.w = fmaxf((v.w - m.w) * sA, 0.f);
                }
                if constexpr (PN == 2) {
                    float4 v2 = reinterpret_cast<const float4*>(Xb + (size_t)(row0 + r) * K)[col4];
                    float4 m2 = reinterpret_cast<const float4*>(muB)[col4];
                    v.x += fmaxf((v2.x - m2.x) * sB, 0.f);
                    v.y += fmaxf((v2.y - m2.y) * sB, 0.f);
                    v.z += fmaxf((v2.z - m2.z) * sB, 0.f);
                    v.w += fmaxf((v2.w - m2.w) * sB, 0.f);
                }
            }
            xlds[r][c4 * 4 + 0] = v.x;
            xlds[r][c4 * 4 + 1] = v.y;
            xlds[r][c4 * 4 + 2] = v.z;
            xlds[r][c4 * 4 + 3] = v.w;
        }
        __syncthreads();

        for (int k = 0; k < BK; ++k) {
            float4 w0 = *reinterpret_cast<const float4*>(&wlds[k * COLS + c0]);
            float4 w1 = *reinterpret_cast<const float4*>(&wlds[k * COLS + c0 + 4]);
#pragma unroll
            for (int i = 0; i < RPT; ++i) {
                float xv = xlds[r0 + i][k];
                acc[i][0] += xv * w0.x;
                acc[i][1] += xv * w0.y;
                acc[i][2] += xv * w0.z;
                acc[i][3] += xv * w0.w;
                acc[i][4] += xv * w1.x;
                acc[i][5] += xv * w1.y;
                acc[i][6] += xv * w1.z;
                acc[i][7] += xv * w1.w;
            }
        }
        __syncthreads();
    }

    float bv[8];
#pragma unroll
    for (int j = 0; j < 8; ++j) bv[j] = bias[c0 + j];

#pragma unroll
    for (int i = 0; i < RPT; ++i) {
        int row = row0 + r0 + i;
        if (row < nrows) {
#pragma unroll
            for (int j = 0; j < 8; ++j) acc[i][j] += bv[j];
            if constexpr (OUTBF) {
                uint4 q;
                q.x = pack2(acc[i][0], acc[i][1]);
                q.y = pack2(acc[i][2], acc[i][3]);
                q.z = pack2(acc[i][4], acc[i][5]);
                q.w = pack2(acc[i][6], acc[i][7]);
                // slice-major: uint[slice=c0/16][row][ (c0/2)&7 .. +3 ]
                size_t uidx = (size_t)(c0 >> 4) * ((size_t)N_NODES * 8) + (size_t)row * 8 +
                              ((c0 >> 1) & 7);
                *reinterpret_cast<uint4*>((unsigned*)Yv + uidx) = q;
            } else {
                // f32 slice-major: float[slice=c0/8][row][0..7]
                size_t fidx = (size_t)(c0 >> 3) * ((size_t)N_NODES * 8) + (size_t)row * 8;
                float4* yp = reinterpret_cast<float4*>((float*)Yv + fidx);
                yp[0] = make_float4(acc[i][0], acc[i][1], acc[i][2], acc[i][3]);
                yp[1] = make_float4(acc[i][4], acc[i][5], acc[i][6], acc[i][7]);
            }
        }
    }
}

// ---------------- CSR build ----------------
__global__ __launch_bounds__(256) void hist_kernel(const int* __restrict__ dst,
                                                   int* __restrict__ counts) {
    int e = blockIdx.x * blockDim.x + threadIdx.x;
    const int stride = gridDim.x * blockDim.x;
    for (; e < N_EDGES; e += stride) atomicAdd(&counts[dst[e]], 1);
}

// single-block scan, int4-widened: 4096 elems per iteration
__global__ __launch_bounds__(1024) void scan_kernel(const int* __restrict__ counts,
                                                    int* __restrict__ rowptr) {
    __shared__ int wsum[16];
    const int tid = threadIdx.x;
    const int lane = tid & 63;
    const int w = tid >> 6;
    int offset = 0;
    if (tid == 0) rowptr[0] = 0;
    for (int base = 0; base < N_NODES; base += 4096) {
        int i = base + tid * 4;
        int4 v = make_int4(0, 0, 0, 0);
        if (i < N_NODES) v = *reinterpret_cast<const int4*>(counts + i);
        int p0 = v.x, p1 = p0 + v.y, p2 = p1 + v.z, p3 = p2 + v.w;
        int incl = p3;
#pragma unroll
        for (int d = 1; d < 64; d <<= 1) {
            int t = __shfl_up(incl, d, 64);
            if (lane >= d) incl += t;
        }
        if (lane == 63) wsum[w] = incl;
        __syncthreads();
        if (w == 0 && lane < 16) {
            int t = wsum[lane];
#pragma unroll
            for (int d = 1; d < 16; d <<= 1) {
                int u = __shfl_up(t, d, 64);
                if (lane >= d) t += u;
            }
            wsum[lane] = t;
        }
        __syncthreads();
        int woff = (w == 0) ? 0 : wsum[w - 1];
        int chunk_total = wsum[15];
        int tbase = offset + woff + incl - p3;
        if (i < N_NODES) {
            rowptr[i + 1] = tbase + p0;
            rowptr[i + 2] = tbase + p1;
            rowptr[i + 3] = tbase + p2;
            rowptr[i + 4] = tbase + p3;
        }
        offset += chunk_total;
        __syncthreads();
    }
}

// XCD-binned bucket: block handles only dst in its bin -> em lines assembled in one L2
__global__ __launch_bounds__(256) void bucket_kernel(const int* __restrict__ src,
                                                     const int* __restrict__ dst,
                                                     const float* __restrict__ ew,
                                                     const int* __restrict__ rowptr,
                                                     int* __restrict__ fill,
                                                     int2* __restrict__ em) {
    const int myBin = blockIdx.x & (NBINS - 1);
    const int lo = myBin * BINW;
    const int hi = lo + BINW;
    int e = (blockIdx.x >> 3) * 256 + threadIdx.x;
    const int stride = (gridDim.x >> 3) * 256;
    for (; e < N_EDGES; e += stride) {
        int d = dst[e];
        if (d >= lo && d < hi) {
            int pos = atomicAdd(&fill[d], 1);
            em[rowptr[d] + pos] = make_int2(src[e], __float_as_int(ew[e]));
        }
    }
}

// ---------------- sliced gather aggregation: slice = blockIdx&7 -> pinned XCD ----------------
// BF16H: H is uint[8][N][8] (bf16 pairs), Bout = [N][128] f32, optional fused stats.
// !BF16H: H is float[8][N][8], Bout = [N][64] f32.
template <bool BF16H, bool STATS>
__global__ __launch_bounds__(256) void agg_sliced(const void* __restrict__ Hv,
                                                  const int* __restrict__ rowptr,
                                                  const int2* __restrict__ em,
                                                  float* __restrict__ Bout,
                                                  float* __restrict__ cs_part,
                                                  float* __restrict__ ss_part) {
    __shared__ float cs[4][16];
    __shared__ float ssw[4];
    const int slice = blockIdx.x & 7;
    const int grp = blockIdx.x >> 3;  // node group of 8
    const int wv = threadIdx.x >> 6;
    const int lane = threadIdx.x & 63;
    const int g = lane >> 3;  // edge sub-group
    const int f = lane & 7;   // feature word within slice
    const unsigned* __restrict__ hpu =
        (const unsigned*)Hv + (size_t)slice * ((size_t)N_NODES * 8);
    const float* __restrict__ hpf = (const float*)Hv + (size_t)slice * ((size_t)N_NODES * 8);

    float csx = 0.f, csy = 0.f, ssacc = 0.f;

#pragma unroll
    for (int nn = 0; nn < 2; ++nn) {
        const int node = grp * 8 + nn * 4 + wv;
        const int beg = rowptr[node];
        const int end = rowptr[node + 1];
        float ax = 0.f, ay = 0.f;
        for (int c = beg; c < end; c += 64) {
            int2 m = (c + lane < end) ? em[c + lane] : make_int2(0, 0);
            const int cnt = min(64, end - c);
            for (int j = 0; j < cnt; j += 8) {
                int s = __shfl(m.x, j + g, 64);
                float w = __int_as_float(__shfl(m.y, j + g, 64));  // 0 for padded lanes
                if constexpr (BF16H) {
                    unsigned u = hpu[(size_t)s * 8 + f];
                    ax += w * __uint_as_float(u << 16);
                    ay += w * __uint_as_float(u & 0xffff0000u);
                } else {
                    ax += w * hpf[(size_t)s * 8 + f];
                }
            }
        }
        // reduce across the 8 edge sub-groups (lane bits 8,16,32)
        ax += __shfl_xor(ax, 8, 64);
        ax += __shfl_xor(ax, 16, 64);
        ax += __shfl_xor(ax, 32, 64);
        if constexpr (BF16H) {
            ay += __shfl_xor(ay, 8, 64);
            ay += __shfl_xor(ay, 16, 64);
            ay += __shfl_xor(ay, 32, 64);
        }
        if (lane < 8) {
            if constexpr (BF16H) {
                reinterpret_cast<float2*>(Bout + (size_t)node * DH + slice * 16)[f] =
                    make_float2(ax, ay);
            } else {
                Bout[(size_t)node * DOUT + slice * 8 + f] = ax;
            }
            if constexpr (STATS) {
                csx += ax;
                csy += ay;
                ssacc += ax * ax + ay * ay;
            }
        }
    }

    if constexpr (STATS) {
        // sum ssacc across the 8 f-lanes (bits 1,2,4); only lanes 0..7 hold data
        ssacc += __shfl_xor(ssacc, 1, 64);
        ssacc += __shfl_xor(ssacc, 2, 64);
        ssacc += __shfl_xor(ssacc, 4, 64);
        if (lane < 8) {
            cs[wv][f * 2] = csx;
            cs[wv][f * 2 + 1] = csy;
        }
        if (lane == 0) ssw[wv] = ssacc;
        __syncthreads();
        const int rep = grp & (NREP - 1);
        if (threadIdx.x < 16) {
            float s =
                cs[0][threadIdx.x] + cs[1][threadIdx.x] + cs[2][threadIdx.x] + cs[3][threadIdx.x];
            atomicAdd(&cs_part[rep * 128 + slice * 16 + threadIdx.x], s);
        }
        if (threadIdx.x == 0) atomicAdd(&ss_part[rep], ssw[0] + ssw[1] + ssw[2] + ssw[3]);
    }
}

// ---------------- finalize: reduce replicas -> mu, inv ----------------
__global__ void finalize_stats(const float* __restrict__ cs_part,
                               const float* __restrict__ ss_part, float* __restrict__ mu,
                               float* __restrict__ inv) {
    const int t = threadIdx.x;  // 128 threads
    float m = 0.f;
    for (int r = 0; r < NREP; ++r) m += cs_part[r * 128 + t];
    float mean = m / (float)N_NODES;
    mu[t] = mean;
    float v = mean * mean;
    __shared__ float partl[2];
    __shared__ float sstot;
#pragma unroll
    for (int off = 32; off; off >>= 1) v += __shfl_down(v, off, 64);
    if ((t & 63) == 0) partl[t >> 6] = v;
    float ss = (t < NREP) ? ss_part[t] : 0.f;
#pragma unroll
    for (int off = 32; off; off >>= 1) ss += __shfl_down(ss, off, 64);
    if (t == 0) sstot = ss;
    __syncthreads();
    if (t == 0) {
        float musq = partl[0] + partl[1];
        float s = (sstot - (float)N_NODES * musq) / (float)N_NODES;
        inv[0] = rsqrtf(EPS + s);
    }
}

extern "C" void kernel_launch(void* const* d_in, const int* in_sizes, int n_in,
                              void* d_out, int out_size, void* d_ws, size_t ws_size,
                              hipStream_t stream) {
    const float* x = (const float*)d_in[0];
    const int* edge_index = (const int*)d_in[1];
    const float* ew = (const float*)d_in[2];
    const float* W0 = (const float*)d_in[3];
    const float* b0 = (const float*)d_in[4];
    const float* W1 = (const float*)d_in[5];
    const float* b1 = (const float*)d_in[6];
    const float* Wout = (const float*)d_in[7];
    const float* bout = (const float*)d_in[8];

    const int* src = edge_index;
    const int* dst = edge_index + N_EDGES;
    float* out = (float*)d_out;

    // workspace layout
    float* base = (float*)d_ws;
    unsigned* Hb = (unsigned*)base;               // sliced bf16 H: uint[8][N][8], aliased w/ HOUT
    float* HOUT = base;                           // sliced f32 H: float[8][N][8]
    float* B1 = base + (size_t)N_NODES * 64;      // N*128 row-major
    float* B2 = B1 + (size_t)N_NODES * DH;        // N*128 row-major
    int2* em = (int2*)(B2 + (size_t)N_NODES * DH);  // E int2
    int* counts = (int*)(em + N_EDGES);           // N
    int* fill = counts + N_NODES;                 // N
    int* rowptr = fill + N_NODES;                 // N+1
    size_t soff = (size_t)(rowptr + N_NODES + 1 - (int*)base);
    soff = (soff + 3) & ~(size_t)3;
    float* stats = base + soff;
    float* cs_part1 = stats;                  // NREP*128
    float* ss_part1 = cs_part1 + NREP * 128;  // NREP
    float* cs_part2 = ss_part1 + NREP;        // NREP*128
    float* ss_part2 = cs_part2 + NREP * 128;  // NREP
    float* mu1 = ss_part2 + NREP;             // 128
    float* inv1 = mu1 + 128;                  // 1 (+3 pad)
    float* mu2 = inv1 + 4;                    // 128
    float* inv2 = mu2 + 128;                  // 1

    const int gemm_grid = (N_NODES + 63) / 64;
    const int agg_grid = (N_NODES / 8) * 8;  // 100000 blocks: 12500 groups x 8 slices

    // zero init
    hipMemsetAsync(counts, 0, (size_t)2 * N_NODES * sizeof(int), stream);  // counts + fill
    hipMemsetAsync(stats, 0, (size_t)2 * (NREP * 128 + NREP) * sizeof(float), stream);

    // CSR build (dst-ordered)
    hist_kernel<<<2048, 256, 0, stream>>>(dst, counts);
    scan_kernel<<<1, 1024, 0, stream>>>(counts, rowptr);
    bucket_kernel<<<2048, 256, 0, stream>>>(src, dst, ew, rowptr, fill, em);

    // Layer 1
    gemm_kernel<128, 0, true><<<gemm_grid, 256, 0, stream>>>(
        x, nullptr, nullptr, nullptr, nullptr, nullptr, W0, b0, Hb, N_NODES);
    agg_sliced<true, true><<<agg_grid, 256, 0, stream>>>(Hb, rowptr, em, B1, cs_part1, ss_part1);
    finalize_stats<<<1, 128, 0, stream>>>(cs_part1, ss_part1, mu1, inv1);

    // Layer 2
    gemm_kernel<128, 1, true><<<gemm_grid, 256, 0, stream>>>(
        B1, mu1, inv1, nullptr, nullptr, nullptr, W1, b1, Hb, N_NODES);
    agg_sliced<true, true><<<agg_grid, 256, 0, stream>>>(Hb, rowptr, em, B2, cs_part2, ss_part2);
    finalize_stats<<<1, 128, 0, stream>>>(cs_part2, ss_part2, mu2, inv2);

    // Output layer
    gemm_kernel<64, 2, false><<<gemm_grid, 256, 0, stream>>>(
        B2, mu2, inv2, B1, mu1, inv1, Wout, bout, HOUT, N_NODES);
    agg_sliced<false, false><<<agg_grid, 256, 0, stream>>>(HOUT, rowptr, em, out, nullptr,
                                                           nullptr);
}

// Round 6
// 610.095 us; speedup vs baseline: 2.0792x; 2.0792x over previous
//
#include <hip/hip_runtime.h>

#define N_NODES 100000
#define N_EDGES 1600000
#define DH 128
#define DOUT 64
#define EPS 1e-6f
#define NBINS 8
#define BINW 12500  // ceil(N_NODES / NBINS)
#define NREP 64     // stats replica buffers

__device__ inline unsigned bfround(float f) {  // f32 -> bf16 bits, round-nearest-even
    unsigned u = __float_as_uint(f);
    return (u + 0x7fffu + ((u >> 16) & 1u)) >> 16;
}
__device__ inline unsigned pack2(float a, float b) { return bfround(a) | (bfround(b) << 16); }

// ---------------- GEMM: Y[nrows, COLS] = f(X)[nrows,128] @ W[128,COLS] + b ----------------
// PN=0: f(X)=Xa.  PN=1: f(X)=relu((Xa-muA)*invA).  PN=2: ...+relu((Xb-muB)*invB)
// OUTBF: write packed bf16 row-major uint[nrows][COLS/2].
template <int COLS, int PN, bool OUTBF>
__global__ __launch_bounds__(256) void gemm_kernel(const float* __restrict__ Xa,
                                                   const float* __restrict__ muA,
                                                   const float* __restrict__ invA,
                                                   const float* __restrict__ Xb,
                                                   const float* __restrict__ muB,
                                                   const float* __restrict__ invB,
                                                   const float* __restrict__ W,
                                                   const float* __restrict__ bias,
                                                   void* __restrict__ Yv, int nrows) {
    constexpr int K = 128;
    constexpr int BK = 64;
    constexpr int COLG = COLS / 8;
    constexpr int ROWG = 256 / COLG;
    constexpr int RPT = 64 / ROWG;

    __shared__ float wlds[BK * COLS];
    __shared__ float xlds[64][BK + 1];

    const int tid = threadIdx.x;
    const int row0 = blockIdx.x * 64;

    const float sA = (PN >= 1) ? invA[0] : 0.f;
    const float sB = (PN == 2) ? invB[0] : 0.f;

    const int colg = tid % COLG;
    const int rowg = tid / COLG;
    const int c0 = colg * 8;
    const int r0 = rowg * RPT;

    float acc[RPT][8];
#pragma unroll
    for (int i = 0; i < RPT; ++i)
#pragma unroll
        for (int j = 0; j < 8; ++j) acc[i][j] = 0.f;

    for (int kb = 0; kb < K; kb += BK) {
        constexpr int WVEC = BK * COLS / 4;
        for (int i = tid; i < WVEC; i += 256) {
            int kr = i / (COLS / 4);
            int c4 = i % (COLS / 4);
            reinterpret_cast<float4*>(wlds)[i] =
                reinterpret_cast<const float4*>(W)[(size_t)(kb + kr) * (COLS / 4) + c4];
        }
        for (int i = tid; i < 64 * (BK / 4); i += 256) {
            int r = i / (BK / 4);
            int c4 = i % (BK / 4);
            int col4 = kb / 4 + c4;
            float4 v = make_float4(0.f, 0.f, 0.f, 0.f);
            if (row0 + r < nrows) {
                v = reinterpret_cast<const float4*>(Xa + (size_t)(row0 + r) * K)[col4];
                if constexpr (PN >= 1) {
                    float4 m = reinterpret_cast<const float4*>(muA)[col4];
                    v.x = fmaxf((v.x - m.x) * sA, 0.f);
                    v.y = fmaxf((v.y - m.y) * sA, 0.f);
                    v.z = fmaxf((v.z - m.z) * sA, 0.f);
                    v.w = fmaxf((v.w - m.w) * sA, 0.f);
                }
                if constexpr (PN == 2) {
                    float4 v2 = reinterpret_cast<const float4*>(Xb + (size_t)(row0 + r) * K)[col4];
                    float4 m2 = reinterpret_cast<const float4*>(muB)[col4];
                    v.x += fmaxf((v2.x - m2.x) * sB, 0.f);
                    v.y += fmaxf((v2.y - m2.y) * sB, 0.f);
                    v.z += fmaxf((v2.z - m2.z) * sB, 0.f);
                    v.w += fmaxf((v2.w - m2.w) * sB, 0.f);
                }
            }
            xlds[r][c4 * 4 + 0] = v.x;
            xlds[r][c4 * 4 + 1] = v.y;
            xlds[r][c4 * 4 + 2] = v.z;
            xlds[r][c4 * 4 + 3] = v.w;
        }
        __syncthreads();

        for (int k = 0; k < BK; ++k) {
            float4 w0 = *reinterpret_cast<const float4*>(&wlds[k * COLS + c0]);
            float4 w1 = *reinterpret_cast<const float4*>(&wlds[k * COLS + c0 + 4]);
#pragma unroll
            for (int i = 0; i < RPT; ++i) {
                float xv = xlds[r0 + i][k];
                acc[i][0] += xv * w0.x;
                acc[i][1] += xv * w0.y;
                acc[i][2] += xv * w0.z;
                acc[i][3] += xv * w0.w;
                acc[i][4] += xv * w1.x;
                acc[i][5] += xv * w1.y;
                acc[i][6] += xv * w1.z;
                acc[i][7] += xv * w1.w;
            }
        }
        __syncthreads();
    }

    float bv[8];
#pragma unroll
    for (int j = 0; j < 8; ++j) bv[j] = bias[c0 + j];

#pragma unroll
    for (int i = 0; i < RPT; ++i) {
        int row = row0 + r0 + i;
        if (row < nrows) {
#pragma unroll
            for (int j = 0; j < 8; ++j) acc[i][j] += bv[j];
            if constexpr (OUTBF) {
                uint4 q;
                q.x = pack2(acc[i][0], acc[i][1]);
                q.y = pack2(acc[i][2], acc[i][3]);
                q.z = pack2(acc[i][4], acc[i][5]);
                q.w = pack2(acc[i][6], acc[i][7]);
                *reinterpret_cast<uint4*>((unsigned*)Yv + (size_t)row * (COLS / 2) + (c0 >> 1)) = q;
            } else {
                float4 o0 = make_float4(acc[i][0], acc[i][1], acc[i][2], acc[i][3]);
                float4 o1 = make_float4(acc[i][4], acc[i][5], acc[i][6], acc[i][7]);
                float4* yp = reinterpret_cast<float4*>((float*)Yv + (size_t)row * COLS + c0);
                yp[0] = o0;
                yp[1] = o1;
            }
        }
    }
}

// ---------------- CSR build ----------------
__global__ __launch_bounds__(256) void hist_kernel(const int* __restrict__ dst,
                                                   int* __restrict__ counts) {
    int e = blockIdx.x * blockDim.x + threadIdx.x;
    const int stride = gridDim.x * blockDim.x;
    for (; e < N_EDGES; e += stride) atomicAdd(&counts[dst[e]], 1);
}

// single-block scan, int4-widened: 4096 elems per iteration
__global__ __launch_bounds__(1024) void scan_kernel(const int* __restrict__ counts,
                                                    int* __restrict__ rowptr) {
    __shared__ int wsum[16];
    const int tid = threadIdx.x;
    const int lane = tid & 63;
    const int w = tid >> 6;
    int offset = 0;
    if (tid == 0) rowptr[0] = 0;
    for (int base = 0; base < N_NODES; base += 4096) {
        int i = base + tid * 4;
        int4 v = make_int4(0, 0, 0, 0);
        if (i < N_NODES) v = *reinterpret_cast<const int4*>(counts + i);
        int p0 = v.x, p1 = p0 + v.y, p2 = p1 + v.z, p3 = p2 + v.w;
        int incl = p3;
#pragma unroll
        for (int d = 1; d < 64; d <<= 1) {
            int t = __shfl_up(incl, d, 64);
            if (lane >= d) incl += t;
        }
        if (lane == 63) wsum[w] = incl;
        __syncthreads();
        if (w == 0 && lane < 16) {
            int t = wsum[lane];
#pragma unroll
            for (int d = 1; d < 16; d <<= 1) {
                int u = __shfl_up(t, d, 64);
                if (lane >= d) t += u;
            }
            wsum[lane] = t;
        }
        __syncthreads();
        int woff = (w == 0) ? 0 : wsum[w - 1];
        int chunk_total = wsum[15];
        int tbase = offset + woff + incl - p3;
        if (i < N_NODES) {
            rowptr[i + 1] = tbase + p0;
            rowptr[i + 2] = tbase + p1;
            rowptr[i + 3] = tbase + p2;
            rowptr[i + 4] = tbase + p3;
        }
        offset += chunk_total;
        __syncthreads();
    }
}

// XCD-binned bucket: block handles only dst in its bin -> em lines assembled in one L2
__global__ __launch_bounds__(256) void bucket_kernel(const int* __restrict__ src,
                                                     const int* __restrict__ dst,
                                                     const float* __restrict__ ew,
                                                     const int* __restrict__ rowptr,
                                                     int* __restrict__ fill,
                                                     int2* __restrict__ em) {
    const int myBin = blockIdx.x & (NBINS - 1);
    const int lo = myBin * BINW;
    const int hi = lo + BINW;
    int e = (blockIdx.x >> 3) * 256 + threadIdx.x;
    const int stride = (gridDim.x >> 3) * 256;
    for (; e < N_EDGES; e += stride) {
        int d = dst[e];
        if (d >= lo && d < hi) {
            int pos = atomicAdd(&fill[d], 1);
            em[rowptr[d] + pos] = make_int2(src[e], __float_as_int(ew[e]));
        }
    }
}

// ------- gather aggregation (bf16 H, 128 cols), 8 loads in flight + fused stats -------
__global__ __launch_bounds__(256) void agg128b_kernel(const unsigned* __restrict__ Hb,
                                                      const int* __restrict__ rowptr,
                                                      const int2* __restrict__ em,
                                                      float* __restrict__ B,
                                                      float* __restrict__ cs_part,
                                                      float* __restrict__ ss_part) {
    __shared__ float cs[4][128];
    __shared__ float ssw[4];
    const int wv = threadIdx.x >> 6;
    const int lane = threadIdx.x & 63;
    const int node = blockIdx.x * 4 + wv;  // grid covers exactly N
    const int beg = rowptr[node];
    const int end = rowptr[node + 1];
    float ax0 = 0.f, ay0 = 0.f, ax1 = 0.f, ay1 = 0.f;
    for (int c = beg; c < end; c += 64) {
        int2 m = (c + lane < end) ? em[c + lane] : make_int2(0, 0);
        const int cnt = min(64, end - c);
        int k = 0;
        for (; k + 8 <= cnt; k += 8) {
#pragma unroll
            for (int j = 0; j < 8; j += 2) {
                int s0 = __shfl(m.x, k + j, 64);
                float w0 = __int_as_float(__shfl(m.y, k + j, 64));
                int s1 = __shfl(m.x, k + j + 1, 64);
                float w1 = __int_as_float(__shfl(m.y, k + j + 1, 64));
                unsigned u0 = Hb[(size_t)s0 * 64 + lane];
                unsigned u1 = Hb[(size_t)s1 * 64 + lane];
                ax0 += w0 * __uint_as_float(u0 << 16);
                ay0 += w0 * __uint_as_float(u0 & 0xffff0000u);
                ax1 += w1 * __uint_as_float(u1 << 16);
                ay1 += w1 * __uint_as_float(u1 & 0xffff0000u);
            }
        }
        for (; k < cnt; ++k) {
            int s = __shfl(m.x, k, 64);
            float w = __int_as_float(__shfl(m.y, k, 64));
            unsigned u = Hb[(size_t)s * 64 + lane];
            ax0 += w * __uint_as_float(u << 16);
            ay0 += w * __uint_as_float(u & 0xffff0000u);
        }
    }
    float2 acc = make_float2(ax0 + ax1, ay0 + ay1);
    reinterpret_cast<float2*>(B + (size_t)node * DH)[lane] = acc;

    // fused stats: per-block reduce then replica atomics
    cs[wv][lane * 2] = acc.x;
    cs[wv][lane * 2 + 1] = acc.y;
    float sq = acc.x * acc.x + acc.y * acc.y;
#pragma unroll
    for (int off = 32; off; off >>= 1) sq += __shfl_down(sq, off, 64);
    if (lane == 0) ssw[wv] = sq;
    __syncthreads();
    const int rep = blockIdx.x & (NREP - 1);
    if (threadIdx.x < 128) {
        float s = cs[0][threadIdx.x] + cs[1][threadIdx.x] + cs[2][threadIdx.x] + cs[3][threadIdx.x];
        atomicAdd(&cs_part[rep * 128 + threadIdx.x], s);
    }
    if (threadIdx.x == 0) atomicAdd(&ss_part[rep], ssw[0] + ssw[1] + ssw[2] + ssw[3]);
}

// ------- gather aggregation (bf16 H, 64 cols): 2 edges per wave-load, 8 in flight -------
__global__ __launch_bounds__(256) void agg64b_kernel(const unsigned* __restrict__ Hb,
                                                     const int* __restrict__ rowptr,
                                                     const int2* __restrict__ em,
                                                     float* __restrict__ out) {
    const int wv = threadIdx.x >> 6;
    const int lane = threadIdx.x & 63;
    const int half = lane >> 5;  // 0: even edge, 1: odd edge
    const int col = lane & 31;   // bf16-pair index (covers cols 2col, 2col+1)
    const int node = blockIdx.x * 4 + wv;
    const int beg = rowptr[node];
    const int end = rowptr[node + 1];
    float ax0 = 0.f, ay0 = 0.f, ax1 = 0.f, ay1 = 0.f;
    for (int c = beg; c < end; c += 64) {
        int2 m = (c + lane < end) ? em[c + lane] : make_int2(0, 0);  // pad -> w=0, s=0
        const int cnt = min(64, end - c);
        int k = 0;
        for (; k + 8 <= cnt; k += 8) {
#pragma unroll
            for (int j = 0; j < 8; j += 4) {
                int i0 = k + j + half;
                int i1 = k + j + 2 + half;
                int s0 = __shfl(m.x, i0, 64);
                float w0 = __int_as_float(__shfl(m.y, i0, 64));
                int s1 = __shfl(m.x, i1, 64);
                float w1 = __int_as_float(__shfl(m.y, i1, 64));
                unsigned u0 = Hb[(size_t)s0 * 32 + col];
                unsigned u1 = Hb[(size_t)s1 * 32 + col];
                ax0 += w0 * __uint_as_float(u0 << 16);
                ay0 += w0 * __uint_as_float(u0 & 0xffff0000u);
                ax1 += w1 * __uint_as_float(u1 << 16);
                ay1 += w1 * __uint_as_float(u1 & 0xffff0000u);
            }
        }
        for (; k < cnt; k += 2) {
            int i0 = k + half;  // may be == cnt for odd tail: padded m gives w=0
            int s0 = __shfl(m.x, i0, 64);
            float w0 = __int_as_float(__shfl(m.y, i0, 64));
            unsigned u0 = Hb[(size_t)s0 * 32 + col];
            ax0 += w0 * __uint_as_float(u0 << 16);
            ay0 += w0 * __uint_as_float(u0 & 0xffff0000u);
        }
    }
    float ax = ax0 + ax1, ay = ay0 + ay1;
    ax += __shfl_xor(ax, 32, 64);  // combine even/odd edge halves
    ay += __shfl_xor(ay, 32, 64);
    if (lane < 32) {
        reinterpret_cast<float2*>(out + (size_t)node * DOUT)[col] = make_float2(ax, ay);
    }
}

// ---------------- finalize: reduce replicas -> mu, inv ----------------
__global__ void finalize_stats(const float* __restrict__ cs_part,
                               const float* __restrict__ ss_part, float* __restrict__ mu,
                               float* __restrict__ inv) {
    const int t = threadIdx.x;  // 128 threads
    float m = 0.f;
    for (int r = 0; r < NREP; ++r) m += cs_part[r * 128 + t];
    float mean = m / (float)N_NODES;
    mu[t] = mean;
    float v = mean * mean;
    __shared__ float partl[2];
    __shared__ float sstot;
#pragma unroll
    for (int off = 32; off; off >>= 1) v += __shfl_down(v, off, 64);
    if ((t & 63) == 0) partl[t >> 6] = v;
    float ss = (t < NREP) ? ss_part[t] : 0.f;
#pragma unroll
    for (int off = 32; off; off >>= 1) ss += __shfl_down(ss, off, 64);
    if (t == 0) sstot = ss;
    __syncthreads();
    if (t == 0) {
        float musq = partl[0] + partl[1];
        float s = (sstot - (float)N_NODES * musq) / (float)N_NODES;
        inv[0] = rsqrtf(EPS + s);
    }
}

extern "C" void kernel_launch(void* const* d_in, const int* in_sizes, int n_in,
                              void* d_out, int out_size, void* d_ws, size_t ws_size,
                              hipStream_t stream) {
    const float* x = (const float*)d_in[0];
    const int* edge_index = (const int*)d_in[1];
    const float* ew = (const float*)d_in[2];
    const float* W0 = (const float*)d_in[3];
    const float* b0 = (const float*)d_in[4];
    const float* W1 = (const float*)d_in[5];
    const float* b1 = (const float*)d_in[6];
    const float* Wout = (const float*)d_in[7];
    const float* bout = (const float*)d_in[8];

    const int* src = edge_index;
    const int* dst = edge_index + N_EDGES;
    float* out = (float*)d_out;

    // workspace layout
    float* base = (float*)d_ws;
    unsigned* Hb = (unsigned*)base;                 // bf16 H: uint[N][64]; HOUT aliases uint[N][32]
    float* B1 = base + (size_t)N_NODES * 64;        // N*128 row-major f32
    float* B2 = B1 + (size_t)N_NODES * DH;          // N*128 row-major f32
    int2* em = (int2*)(B2 + (size_t)N_NODES * DH);  // E int2
    int* counts = (int*)(em + N_EDGES);             // N
    int* fill = counts + N_NODES;                   // N
    int* rowptr = fill + N_NODES;                   // N+1
    size_t soff = (size_t)(rowptr + N_NODES + 1 - (int*)base);
    soff = (soff + 3) & ~(size_t)3;
    float* stats = base + soff;
    float* cs_part1 = stats;                  // NREP*128
    float* ss_part1 = cs_part1 + NREP * 128;  // NREP
    float* cs_part2 = ss_part1 + NREP;        // NREP*128
    float* ss_part2 = cs_part2 + NREP * 128;  // NREP
    float* mu1 = ss_part2 + NREP;             // 128
    float* inv1 = mu1 + 128;                  // 1 (+3 pad)
    float* mu2 = inv1 + 4;                    // 128
    float* inv2 = mu2 + 128;                  // 1

    const int gemm_grid = (N_NODES + 63) / 64;
    const int agg_grid = N_NODES / 4;  // 25000 exact

    // zero init
    hipMemsetAsync(counts, 0, (size_t)2 * N_NODES * sizeof(int), stream);  // counts + fill
    hipMemsetAsync(stats, 0, (size_t)2 * (NREP * 128 + NREP) * sizeof(float), stream);

    // CSR build (dst-ordered)
    hist_kernel<<<2048, 256, 0, stream>>>(dst, counts);
    scan_kernel<<<1, 1024, 0, stream>>>(counts, rowptr);
    bucket_kernel<<<2048, 256, 0, stream>>>(src, dst, ew, rowptr, fill, em);

    // Layer 1
    gemm_kernel<128, 0, true><<<gemm_grid, 256, 0, stream>>>(
        x, nullptr, nullptr, nullptr, nullptr, nullptr, W0, b0, Hb, N_NODES);
    agg128b_kernel<<<agg_grid, 256, 0, stream>>>(Hb, rowptr, em, B1, cs_part1, ss_part1);
    finalize_stats<<<1, 128, 0, stream>>>(cs_part1, ss_part1, mu1, inv1);

    // Layer 2
    gemm_kernel<128, 1, true><<<gemm_grid, 256, 0, stream>>>(
        B1, mu1, inv1, nullptr, nullptr, nullptr, W1, b1, Hb, N_NODES);
    agg128b_kernel<<<agg_grid, 256, 0, stream>>>(Hb, rowptr, em, B2, cs_part2, ss_part2);
    finalize_stats<<<1, 128, 0, stream>>>(cs_part2, ss_part2, mu2, inv2);

    // Output layer: HOUT(bf16) = (relu(pn2(B2))+relu(pn1(B1)))@Wout+bout; out = gather
    gemm_kernel<64, 2, true><<<gemm_grid, 256, 0, stream>>>(
        B2, mu2, inv2, B1, mu1, inv1, Wout, bout, Hb, N_NODES);
    agg64b_kernel<<<agg_grid, 256, 0, stream>>>(Hb, rowptr, em, out);
}

// Round 7
// 598.308 us; speedup vs baseline: 2.1202x; 1.0197x over previous
//
#include <hip/hip_runtime.h>

#define N_NODES 100000
#define N_EDGES 1600000
#define DH 128
#define DOUT 64
#define EPS 1e-6f
#define NBINS 8
#define BINW 12500  // ceil(N_NODES / NBINS)
#define NREP 64     // stats replica buffers

__device__ inline unsigned bfround(float f) {  // f32 -> bf16 bits, round-nearest-even
    unsigned u = __float_as_uint(f);
    return (u + 0x7fffu + ((u >> 16) & 1u)) >> 16;
}
__device__ inline unsigned pack2(float a, float b) { return bfround(a) | (bfround(b) << 16); }
__device__ inline float blo(unsigned u) { return __uint_as_float(u << 16); }
__device__ inline float bhi(unsigned u) { return __uint_as_float(u & 0xffff0000u); }

// ---------------- GEMM: Y[nrows, COLS] = f(X)[nrows,128] @ W[128,COLS] + b ----------------
// PN=0: f(X)=Xa.  PN=1: f(X)=relu((Xa-muA)*invA).  PN=2: ...+relu((Xb-muB)*invB)
// OUTBF: write packed bf16 row-major uint[nrows][COLS/2].
template <int COLS, int PN, bool OUTBF>
__global__ __launch_bounds__(256) void gemm_kernel(const float* __restrict__ Xa,
                                                   const float* __restrict__ muA,
                                                   const float* __restrict__ invA,
                                                   const float* __restrict__ Xb,
                                                   const float* __restrict__ muB,
                                                   const float* __restrict__ invB,
                                                   const float* __restrict__ W,
                                                   const float* __restrict__ bias,
                                                   void* __restrict__ Yv, int nrows) {
    constexpr int K = 128;
    constexpr int BK = 64;
    constexpr int COLG = COLS / 8;
    constexpr int ROWG = 256 / COLG;
    constexpr int RPT = 64 / ROWG;

    __shared__ float wlds[BK * COLS];
    __shared__ float xlds[64][BK + 1];

    const int tid = threadIdx.x;
    const int row0 = blockIdx.x * 64;

    const float sA = (PN >= 1) ? invA[0] : 0.f;
    const float sB = (PN == 2) ? invB[0] : 0.f;

    const int colg = tid % COLG;
    const int rowg = tid / COLG;
    const int c0 = colg * 8;
    const int r0 = rowg * RPT;

    float acc[RPT][8];
#pragma unroll
    for (int i = 0; i < RPT; ++i)
#pragma unroll
        for (int j = 0; j < 8; ++j) acc[i][j] = 0.f;

    for (int kb = 0; kb < K; kb += BK) {
        constexpr int WVEC = BK * COLS / 4;
        for (int i = tid; i < WVEC; i += 256) {
            int kr = i / (COLS / 4);
            int c4 = i % (COLS / 4);
            reinterpret_cast<float4*>(wlds)[i] =
                reinterpret_cast<const float4*>(W)[(size_t)(kb + kr) * (COLS / 4) + c4];
        }
        for (int i = tid; i < 64 * (BK / 4); i += 256) {
            int r = i / (BK / 4);
            int c4 = i % (BK / 4);
            int col4 = kb / 4 + c4;
            float4 v = make_float4(0.f, 0.f, 0.f, 0.f);
            if (row0 + r < nrows) {
                v = reinterpret_cast<const float4*>(Xa + (size_t)(row0 + r) * K)[col4];
                if constexpr (PN >= 1) {
                    float4 m = reinterpret_cast<const float4*>(muA)[col4];
                    v.x = fmaxf((v.x - m.x) * sA, 0.f);
                    v.y = fmaxf((v.y - m.y) * sA, 0.f);
                    v.z = fmaxf((v.z - m.z) * sA, 0.f);
                    v.w = fmaxf((v.w - m.w) * sA, 0.f);
                }
                if constexpr (PN == 2) {
                    float4 v2 = reinterpret_cast<const float4*>(Xb + (size_t)(row0 + r) * K)[col4];
                    float4 m2 = reinterpret_cast<const float4*>(muB)[col4];
                    v.x += fmaxf((v2.x - m2.x) * sB, 0.f);
                    v.y += fmaxf((v2.y - m2.y) * sB, 0.f);
                    v.z += fmaxf((v2.z - m2.z) * sB, 0.f);
                    v.w += fmaxf((v2.w - m2.w) * sB, 0.f);
                }
            }
            xlds[r][c4 * 4 + 0] = v.x;
            xlds[r][c4 * 4 + 1] = v.y;
            xlds[r][c4 * 4 + 2] = v.z;
            xlds[r][c4 * 4 + 3] = v.w;
        }
        __syncthreads();

        for (int k = 0; k < BK; ++k) {
            float4 w0 = *reinterpret_cast<const float4*>(&wlds[k * COLS + c0]);
            float4 w1 = *reinterpret_cast<const float4*>(&wlds[k * COLS + c0 + 4]);
#pragma unroll
            for (int i = 0; i < RPT; ++i) {
                float xv = xlds[r0 + i][k];
                acc[i][0] += xv * w0.x;
                acc[i][1] += xv * w0.y;
                acc[i][2] += xv * w0.z;
                acc[i][3] += xv * w0.w;
                acc[i][4] += xv * w1.x;
                acc[i][5] += xv * w1.y;
                acc[i][6] += xv * w1.z;
                acc[i][7] += xv * w1.w;
            }
        }
        __syncthreads();
    }

    float bv[8];
#pragma unroll
    for (int j = 0; j < 8; ++j) bv[j] = bias[c0 + j];

#pragma unroll
    for (int i = 0; i < RPT; ++i) {
        int row = row0 + r0 + i;
        if (row < nrows) {
#pragma unroll
            for (int j = 0; j < 8; ++j) acc[i][j] += bv[j];
            if constexpr (OUTBF) {
                uint4 q;
                q.x = pack2(acc[i][0], acc[i][1]);
                q.y = pack2(acc[i][2], acc[i][3]);
                q.z = pack2(acc[i][4], acc[i][5]);
                q.w = pack2(acc[i][6], acc[i][7]);
                *reinterpret_cast<uint4*>((unsigned*)Yv + (size_t)row * (COLS / 2) + (c0 >> 1)) = q;
            } else {
                float4 o0 = make_float4(acc[i][0], acc[i][1], acc[i][2], acc[i][3]);
                float4 o1 = make_float4(acc[i][4], acc[i][5], acc[i][6], acc[i][7]);
                float4* yp = reinterpret_cast<float4*>((float*)Yv + (size_t)row * COLS + c0);
                yp[0] = o0;
                yp[1] = o1;
            }
        }
    }
}

// ---------------- CSR build ----------------
__global__ __launch_bounds__(256) void hist_kernel(const int* __restrict__ dst,
                                                   int* __restrict__ counts) {
    int e = blockIdx.x * blockDim.x + threadIdx.x;
    const int stride = gridDim.x * blockDim.x;
    for (; e < N_EDGES; e += stride) atomicAdd(&counts[dst[e]], 1);
}

// single-block scan, int4-widened: 4096 elems per iteration
__global__ __launch_bounds__(1024) void scan_kernel(const int* __restrict__ counts,
                                                    int* __restrict__ rowptr) {
    __shared__ int wsum[16];
    const int tid = threadIdx.x;
    const int lane = tid & 63;
    const int w = tid >> 6;
    int offset = 0;
    if (tid == 0) rowptr[0] = 0;
    for (int base = 0; base < N_NODES; base += 4096) {
        int i = base + tid * 4;
        int4 v = make_int4(0, 0, 0, 0);
        if (i < N_NODES) v = *reinterpret_cast<const int4*>(counts + i);
        int p0 = v.x, p1 = p0 + v.y, p2 = p1 + v.z, p3 = p2 + v.w;
        int incl = p3;
#pragma unroll
        for (int d = 1; d < 64; d <<= 1) {
            int t = __shfl_up(incl, d, 64);
            if (lane >= d) incl += t;
        }
        if (lane == 63) wsum[w] = incl;
        __syncthreads();
        if (w == 0 && lane < 16) {
            int t = wsum[lane];
#pragma unroll
            for (int d = 1; d < 16; d <<= 1) {
                int u = __shfl_up(t, d, 64);
                if (lane >= d) t += u;
            }
            wsum[lane] = t;
        }
        __syncthreads();
        int woff = (w == 0) ? 0 : wsum[w - 1];
        int chunk_total = wsum[15];
        int tbase = offset + woff + incl - p3;
        if (i < N_NODES) {
            rowptr[i + 1] = tbase + p0;
            rowptr[i + 2] = tbase + p1;
            rowptr[i + 3] = tbase + p2;
            rowptr[i + 4] = tbase + p3;
        }
        offset += chunk_total;
        __syncthreads();
    }
}

// XCD-binned bucket: block handles only dst in its bin -> em lines assembled in one L2
__global__ __launch_bounds__(256) void bucket_kernel(const int* __restrict__ src,
                                                     const int* __restrict__ dst,
                                                     const float* __restrict__ ew,
                                                     const int* __restrict__ rowptr,
                                                     int* __restrict__ fill,
                                                     int2* __restrict__ em) {
    const int myBin = blockIdx.x & (NBINS - 1);
    const int lo = myBin * BINW;
    const int hi = lo + BINW;
    int e = (blockIdx.x >> 3) * 256 + threadIdx.x;
    const int stride = (gridDim.x >> 3) * 256;
    for (; e < N_EDGES; e += stride) {
        int d = dst[e];
        if (d >= lo && d < hi) {
            int pos = atomicAdd(&fill[d], 1);
            em[rowptr[d] + pos] = make_int2(src[e], __float_as_int(ew[e]));
        }
    }
}

// ------- gather aggregation (bf16 H, 128 cols): SW-pipelined 8-deep + fused stats -------
__global__ __launch_bounds__(256) void agg128b_kernel(const unsigned* __restrict__ Hb,
                                                      const int* __restrict__ rowptr,
                                                      const int2* __restrict__ em,
                                                      float* __restrict__ B,
                                                      float* __restrict__ cs_part,
                                                      float* __restrict__ ss_part) {
    __shared__ float cs[4][128];
    __shared__ float ssw[4];
    const int wv = threadIdx.x >> 6;
    const int lane = threadIdx.x & 63;
    const int node = blockIdx.x * 4 + wv;  // grid covers exactly N
    const int beg = rowptr[node];
    const int end = rowptr[node + 1];
    const int len = end - beg;
    float ax0 = 0.f, ay0 = 0.f, ax1 = 0.f, ay1 = 0.f;

    if (__builtin_expect(len <= 64, 1)) {
        // whole edge list in one coalesced load; pad with (s=0,w=0) -> row0 loads are L1-hot no-ops
        int2 m = (lane < len) ? em[beg + lane] : make_int2(0, 0);
        const int rounds = (len + 7) >> 3;
        for (int g = 0; g < rounds; ++g) {
            const int b = g * 8;
            int s0 = __shfl(m.x, b + 0, 64);
            int s1 = __shfl(m.x, b + 1, 64);
            int s2 = __shfl(m.x, b + 2, 64);
            int s3 = __shfl(m.x, b + 3, 64);
            int s4 = __shfl(m.x, b + 4, 64);
            int s5 = __shfl(m.x, b + 5, 64);
            int s6 = __shfl(m.x, b + 6, 64);
            int s7 = __shfl(m.x, b + 7, 64);
            float w0 = __int_as_float(__shfl(m.y, b + 0, 64));
            float w1 = __int_as_float(__shfl(m.y, b + 1, 64));
            float w2 = __int_as_float(__shfl(m.y, b + 2, 64));
            float w3 = __int_as_float(__shfl(m.y, b + 3, 64));
            float w4 = __int_as_float(__shfl(m.y, b + 4, 64));
            float w5 = __int_as_float(__shfl(m.y, b + 5, 64));
            float w6 = __int_as_float(__shfl(m.y, b + 6, 64));
            float w7 = __int_as_float(__shfl(m.y, b + 7, 64));
            unsigned u0 = Hb[(size_t)s0 * 64 + lane];
            unsigned u1 = Hb[(size_t)s1 * 64 + lane];
            unsigned u2 = Hb[(size_t)s2 * 64 + lane];
            unsigned u3 = Hb[(size_t)s3 * 64 + lane];
            unsigned u4 = Hb[(size_t)s4 * 64 + lane];
            unsigned u5 = Hb[(size_t)s5 * 64 + lane];
            unsigned u6 = Hb[(size_t)s6 * 64 + lane];
            unsigned u7 = Hb[(size_t)s7 * 64 + lane];
            ax0 += w0 * blo(u0); ay0 += w0 * bhi(u0);
            ax1 += w1 * blo(u1); ay1 += w1 * bhi(u1);
            ax0 += w2 * blo(u2); ay0 += w2 * bhi(u2);
            ax1 += w3 * blo(u3); ay1 += w3 * bhi(u3);
            ax0 += w4 * blo(u4); ay0 += w4 * bhi(u4);
            ax1 += w5 * blo(u5); ay1 += w5 * bhi(u5);
            ax0 += w6 * blo(u6); ay0 += w6 * bhi(u6);
            ax1 += w7 * blo(u7); ay1 += w7 * bhi(u7);
        }
    } else {
        for (int c = beg; c < end; c += 64) {
            int2 m = (c + lane < end) ? em[c + lane] : make_int2(0, 0);
            const int cnt = min(64, end - c);
            for (int k = 0; k < cnt; ++k) {
                int s = __shfl(m.x, k, 64);
                float w = __int_as_float(__shfl(m.y, k, 64));
                unsigned u = Hb[(size_t)s * 64 + lane];
                ax0 += w * blo(u);
                ay0 += w * bhi(u);
            }
        }
    }
    float2 acc = make_float2(ax0 + ax1, ay0 + ay1);
    reinterpret_cast<float2*>(B + (size_t)node * DH)[lane] = acc;

    // fused stats: per-block reduce then replica atomics
    cs[wv][lane * 2] = acc.x;
    cs[wv][lane * 2 + 1] = acc.y;
    float sq = acc.x * acc.x + acc.y * acc.y;
#pragma unroll
    for (int off = 32; off; off >>= 1) sq += __shfl_down(sq, off, 64);
    if (lane == 0) ssw[wv] = sq;
    __syncthreads();
    const int rep = blockIdx.x & (NREP - 1);
    if (threadIdx.x < 128) {
        float s = cs[0][threadIdx.x] + cs[1][threadIdx.x] + cs[2][threadIdx.x] + cs[3][threadIdx.x];
        atomicAdd(&cs_part[rep * 128 + threadIdx.x], s);
    }
    if (threadIdx.x == 0) atomicAdd(&ss_part[rep], ssw[0] + ssw[1] + ssw[2] + ssw[3]);
}

// ------- gather aggregation (bf16 H, 64 cols): 2 edges per wave-load, SW-pipelined -------
__global__ __launch_bounds__(256) void agg64b_kernel(const unsigned* __restrict__ Hb,
                                                     const int* __restrict__ rowptr,
                                                     const int2* __restrict__ em,
                                                     float* __restrict__ out) {
    const int wv = threadIdx.x >> 6;
    const int lane = threadIdx.x & 63;
    const int half = lane >> 5;  // 0: even edge, 1: odd edge
    const int col = lane & 31;   // bf16-pair index
    const int node = blockIdx.x * 4 + wv;
    const int beg = rowptr[node];
    const int end = rowptr[node + 1];
    const int len = end - beg;
    float ax0 = 0.f, ay0 = 0.f, ax1 = 0.f, ay1 = 0.f;

    if (__builtin_expect(len <= 64, 1)) {
        int2 m = (lane < len) ? em[beg + lane] : make_int2(0, 0);
        const int rounds = (len + 15) >> 4;  // 16 edges per group = 8 paired loads
        for (int g = 0; g < rounds; ++g) {
            const int b = g * 16 + half;
            int s0 = __shfl(m.x, b + 0, 64);
            int s1 = __shfl(m.x, b + 2, 64);
            int s2 = __shfl(m.x, b + 4, 64);
            int s3 = __shfl(m.x, b + 6, 64);
            int s4 = __shfl(m.x, b + 8, 64);
            int s5 = __shfl(m.x, b + 10, 64);
            int s6 = __shfl(m.x, b + 12, 64);
            int s7 = __shfl(m.x, b + 14, 64);
            float w0 = __int_as_float(__shfl(m.y, b + 0, 64));
            float w1 = __int_as_float(__shfl(m.y, b + 2, 64));
            float w2 = __int_as_float(__shfl(m.y, b + 4, 64));
            float w3 = __int_as_float(__shfl(m.y, b + 6, 64));
            float w4 = __int_as_float(__shfl(m.y, b + 8, 64));
            float w5 = __int_as_float(__shfl(m.y, b + 10, 64));
            float w6 = __int_as_float(__shfl(m.y, b + 12, 64));
            float w7 = __int_as_float(__shfl(m.y, b + 14, 64));
            unsigned u0 = Hb[(size_t)s0 * 32 + col];
            unsigned u1 = Hb[(size_t)s1 * 32 + col];
            unsigned u2 = Hb[(size_t)s2 * 32 + col];
            unsigned u3 = Hb[(size_t)s3 * 32 + col];
            unsigned u4 = Hb[(size_t)s4 * 32 + col];
            unsigned u5 = Hb[(size_t)s5 * 32 + col];
            unsigned u6 = Hb[(size_t)s6 * 32 + col];
            unsigned u7 = Hb[(size_t)s7 * 32 + col];
            ax0 += w0 * blo(u0); ay0 += w0 * bhi(u0);
            ax1 += w1 * blo(u1); ay1 += w1 * bhi(u1);
            ax0 += w2 * blo(u2); ay0 += w2 * bhi(u2);
            ax1 += w3 * blo(u3); ay1 += w3 * bhi(u3);
            ax0 += w4 * blo(u4); ay0 += w4 * bhi(u4);
            ax1 += w5 * blo(u5); ay1 += w5 * bhi(u5);
            ax0 += w6 * blo(u6); ay0 += w6 * bhi(u6);
            ax1 += w7 * blo(u7); ay1 += w7 * bhi(u7);
        }
    } else {
        for (int c = beg; c < end; c += 64) {
            int2 m = (c + lane < end) ? em[c + lane] : make_int2(0, 0);
            const int cnt = min(64, end - c);
            for (int k = 0; k < cnt; k += 2) {
                int i0 = k + half;  // odd tail handled by w=0 padding
                int s0 = __shfl(m.x, i0, 64);
                float w0 = __int_as_float(__shfl(m.y, i0, 64));
                unsigned u0 = Hb[(size_t)s0 * 32 + col];
                ax0 += w0 * blo(u0);
                ay0 += w0 * bhi(u0);
            }
        }
    }
    float ax = ax0 + ax1, ay = ay0 + ay1;
    ax += __shfl_xor(ax, 32, 64);  // combine even/odd edge halves
    ay += __shfl_xor(ay, 32, 64);
    if (lane < 32) {
        reinterpret_cast<float2*>(out + (size_t)node * DOUT)[col] = make_float2(ax, ay);
    }
}

// ---------------- finalize: reduce replicas -> mu, inv ----------------
__global__ void finalize_stats(const float* __restrict__ cs_part,
                               const float* __restrict__ ss_part, float* __restrict__ mu,
                               float* __restrict__ inv) {
    const int t = threadIdx.x;  // 128 threads
    float m = 0.f;
    for (int r = 0; r < NREP; ++r) m += cs_part[r * 128 + t];
    float mean = m / (float)N_NODES;
    mu[t] = mean;
    float v = mean * mean;
    __shared__ float partl[2];
    __shared__ float sstot;
#pragma unroll
    for (int off = 32; off; off >>= 1) v += __shfl_down(v, off, 64);
    if ((t & 63) == 0) partl[t >> 6] = v;
    float ss = (t < NREP) ? ss_part[t] : 0.f;
#pragma unroll
    for (int off = 32; off; off >>= 1) ss += __shfl_down(ss, off, 64);
    if (t == 0) sstot = ss;
    __syncthreads();
    if (t == 0) {
        float musq = partl[0] + partl[1];
        float s = (sstot - (float)N_NODES * musq) / (float)N_NODES;
        inv[0] = rsqrtf(EPS + s);
    }
}

extern "C" void kernel_launch(void* const* d_in, const int* in_sizes, int n_in,
                              void* d_out, int out_size, void* d_ws, size_t ws_size,
                              hipStream_t stream) {
    const float* x = (const float*)d_in[0];
    const int* edge_index = (const int*)d_in[1];
    const float* ew = (const float*)d_in[2];
    const float* W0 = (const float*)d_in[3];
    const float* b0 = (const float*)d_in[4];
    const float* W1 = (const float*)d_in[5];
    const float* b1 = (const float*)d_in[6];
    const float* Wout = (const float*)d_in[7];
    const float* bout = (const float*)d_in[8];

    const int* src = edge_index;
    const int* dst = edge_index + N_EDGES;
    float* out = (float*)d_out;

    // workspace layout
    float* base = (float*)d_ws;
    unsigned* Hb = (unsigned*)base;                 // bf16 H: uint[N][64]; HOUT aliases uint[N][32]
    float* B1 = base + (size_t)N_NODES * 64;        // N*128 row-major f32
    float* B2 = B1 + (size_t)N_NODES * DH;          // N*128 row-major f32
    int2* em = (int2*)(B2 + (size_t)N_NODES * DH);  // E int2
    int* counts = (int*)(em + N_EDGES);             // N
    int* fill = counts + N_NODES;                   // N
    int* rowptr = fill + N_NODES;                   // N+1
    size_t soff = (size_t)(rowptr + N_NODES + 1 - (int*)base);
    soff = (soff + 3) & ~(size_t)3;
    float* stats = base + soff;
    float* cs_part1 = stats;                  // NREP*128
    float* ss_part1 = cs_part1 + NREP * 128;  // NREP
    float* cs_part2 = ss_part1 + NREP;        // NREP*128
    float* ss_part2 = cs_part2 + NREP * 128;  // NREP
    float* mu1 = ss_part2 + NREP;             // 128
    float* inv1 = mu1 + 128;                  // 1 (+3 pad)
    float* mu2 = inv1 + 4;                    // 128
    float* inv2 = mu2 + 128;                  // 1

    const int gemm_grid = (N_NODES + 63) / 64;
    const int agg_grid = N_NODES / 4;  // 25000 exact

    // zero init
    hipMemsetAsync(counts, 0, (size_t)2 * N_NODES * sizeof(int), stream);  // counts + fill
    hipMemsetAsync(stats, 0, (size_t)2 * (NREP * 128 + NREP) * sizeof(float), stream);

    // CSR build (dst-ordered)
    hist_kernel<<<2048, 256, 0, stream>>>(dst, counts);
    scan_kernel<<<1, 1024, 0, stream>>>(counts, rowptr);
    bucket_kernel<<<2048, 256, 0, stream>>>(src, dst, ew, rowptr, fill, em);

    // Layer 1
    gemm_kernel<128, 0, true><<<gemm_grid, 256, 0, stream>>>(
        x, nullptr, nullptr, nullptr, nullptr, nullptr, W0, b0, Hb, N_NODES);
    agg128b_kernel<<<agg_grid, 256, 0, stream>>>(Hb, rowptr, em, B1, cs_part1, ss_part1);
    finalize_stats<<<1, 128, 0, stream>>>(cs_part1, ss_part1, mu1, inv1);

    // Layer 2
    gemm_kernel<128, 1, true><<<gemm_grid, 256, 0, stream>>>(
        B1, mu1, inv1, nullptr, nullptr, nullptr, W1, b1, Hb, N_NODES);
    agg128b_kernel<<<agg_grid, 256, 0, stream>>>(Hb, rowptr, em, B2, cs_part2, ss_part2);
    finalize_stats<<<1, 128, 0, stream>>>(cs_part2, ss_part2, mu2, inv2);

    // Output layer: HOUT(bf16) = (relu(pn2(B2))+relu(pn1(B1)))@Wout+bout; out = gather
    gemm_kernel<64, 2, true><<<gemm_grid, 256, 0, stream>>>(
        B2, mu2, inv2, B1, mu1, inv1, Wout, bout, Hb, N_NODES);
    agg64b_kernel<<<agg_grid, 256, 0, stream>>>(Hb, rowptr, em, out);
}

// Round 8
// 589.867 us; speedup vs baseline: 2.1505x; 1.0143x over previous
//
#include <hip/hip_runtime.h>

#define N_NODES 100000
#define N_EDGES 1600000
#define DH 128
#define DOUT 64
#define EPS 1e-6f
#define NBINS 8
#define BINW 12500  // ceil(N_NODES / NBINS)
#define NREP 64     // stats replica buffers

__device__ inline unsigned bfround(float f) {  // f32 -> bf16 bits, round-nearest-even
    unsigned u = __float_as_uint(f);
    return (u + 0x7fffu + ((u >> 16) & 1u)) >> 16;
}
__device__ inline unsigned pack2(float a, float b) { return bfround(a) | (bfround(b) << 16); }
__device__ inline float blo(unsigned u) { return __uint_as_float(u << 16); }
__device__ inline float bhi(unsigned u) { return __uint_as_float(u & 0xffff0000u); }

// ---------------- GEMM: Y[nrows, COLS] = f(X)[nrows,128] @ W[128,COLS] + b ----------------
// PN=0: f(X)=Xa.  PN=1: f(X)=relu((Xa-muA)*invA).  PN=2: ...+relu((Xb-muB)*invB)
// OUTBF: write packed bf16 row-major uint[nrows][COLS/2].
template <int COLS, int PN, bool OUTBF>
__global__ __launch_bounds__(256) void gemm_kernel(const float* __restrict__ Xa,
                                                   const float* __restrict__ muA,
                                                   const float* __restrict__ invA,
                                                   const float* __restrict__ Xb,
                                                   const float* __restrict__ muB,
                                                   const float* __restrict__ invB,
                                                   const float* __restrict__ W,
                                                   const float* __restrict__ bias,
                                                   void* __restrict__ Yv, int nrows) {
    constexpr int K = 128;
    constexpr int BK = 64;
    constexpr int COLG = COLS / 8;
    constexpr int ROWG = 256 / COLG;
    constexpr int RPT = 64 / ROWG;

    __shared__ float wlds[BK * COLS];
    __shared__ float xlds[64][BK + 1];

    const int tid = threadIdx.x;
    const int row0 = blockIdx.x * 64;

    const float sA = (PN >= 1) ? invA[0] : 0.f;
    const float sB = (PN == 2) ? invB[0] : 0.f;

    const int colg = tid % COLG;
    const int rowg = tid / COLG;
    const int c0 = colg * 8;
    const int r0 = rowg * RPT;

    float acc[RPT][8];
#pragma unroll
    for (int i = 0; i < RPT; ++i)
#pragma unroll
        for (int j = 0; j < 8; ++j) acc[i][j] = 0.f;

    for (int kb = 0; kb < K; kb += BK) {
        constexpr int WVEC = BK * COLS / 4;
        for (int i = tid; i < WVEC; i += 256) {
            int kr = i / (COLS / 4);
            int c4 = i % (COLS / 4);
            reinterpret_cast<float4*>(wlds)[i] =
                reinterpret_cast<const float4*>(W)[(size_t)(kb + kr) * (COLS / 4) + c4];
        }
        for (int i = tid; i < 64 * (BK / 4); i += 256) {
            int r = i / (BK / 4);
            int c4 = i % (BK / 4);
            int col4 = kb / 4 + c4;
            float4 v = make_float4(0.f, 0.f, 0.f, 0.f);
            if (row0 + r < nrows) {
                v = reinterpret_cast<const float4*>(Xa + (size_t)(row0 + r) * K)[col4];
                if constexpr (PN >= 1) {
                    float4 m = reinterpret_cast<const float4*>(muA)[col4];
                    v.x = fmaxf((v.x - m.x) * sA, 0.f);
                    v.y = fmaxf((v.y - m.y) * sA, 0.f);
                    v.z = fmaxf((v.z - m.z) * sA, 0.f);
                    v.w = fmaxf((v.w - m.w) * sA, 0.f);
                }
                if constexpr (PN == 2) {
                    float4 v2 = reinterpret_cast<const float4*>(Xb + (size_t)(row0 + r) * K)[col4];
                    float4 m2 = reinterpret_cast<const float4*>(muB)[col4];
                    v.x += fmaxf((v2.x - m2.x) * sB, 0.f);
                    v.y += fmaxf((v2.y - m2.y) * sB, 0.f);
                    v.z += fmaxf((v2.z - m2.z) * sB, 0.f);
                    v.w += fmaxf((v2.w - m2.w) * sB, 0.f);
                }
            }
            xlds[r][c4 * 4 + 0] = v.x;
            xlds[r][c4 * 4 + 1] = v.y;
            xlds[r][c4 * 4 + 2] = v.z;
            xlds[r][c4 * 4 + 3] = v.w;
        }
        __syncthreads();

        for (int k = 0; k < BK; ++k) {
            float4 w0 = *reinterpret_cast<const float4*>(&wlds[k * COLS + c0]);
            float4 w1 = *reinterpret_cast<const float4*>(&wlds[k * COLS + c0 + 4]);
#pragma unroll
            for (int i = 0; i < RPT; ++i) {
                float xv = xlds[r0 + i][k];
                acc[i][0] += xv * w0.x;
                acc[i][1] += xv * w0.y;
                acc[i][2] += xv * w0.z;
                acc[i][3] += xv * w0.w;
                acc[i][4] += xv * w1.x;
                acc[i][5] += xv * w1.y;
                acc[i][6] += xv * w1.z;
                acc[i][7] += xv * w1.w;
            }
        }
        __syncthreads();
    }

    float bv[8];
#pragma unroll
    for (int j = 0; j < 8; ++j) bv[j] = bias[c0 + j];

#pragma unroll
    for (int i = 0; i < RPT; ++i) {
        int row = row0 + r0 + i;
        if (row < nrows) {
#pragma unroll
            for (int j = 0; j < 8; ++j) acc[i][j] += bv[j];
            if constexpr (OUTBF) {
                uint4 q;
                q.x = pack2(acc[i][0], acc[i][1]);
                q.y = pack2(acc[i][2], acc[i][3]);
                q.z = pack2(acc[i][4], acc[i][5]);
                q.w = pack2(acc[i][6], acc[i][7]);
                *reinterpret_cast<uint4*>((unsigned*)Yv + (size_t)row * (COLS / 2) + (c0 >> 1)) = q;
            } else {
                float4 o0 = make_float4(acc[i][0], acc[i][1], acc[i][2], acc[i][3]);
                float4 o1 = make_float4(acc[i][4], acc[i][5], acc[i][6], acc[i][7]);
                float4* yp = reinterpret_cast<float4*>((float*)Yv + (size_t)row * COLS + c0);
                yp[0] = o0;
                yp[1] = o1;
            }
        }
    }
}

// ---------------- CSR build ----------------
__global__ __launch_bounds__(256) void hist_kernel(const int* __restrict__ dst,
                                                   int* __restrict__ counts) {
    int e = blockIdx.x * blockDim.x + threadIdx.x;
    const int stride = gridDim.x * blockDim.x;
    for (; e < N_EDGES; e += stride) atomicAdd(&counts[dst[e]], 1);
}

// single-block scan, int4-widened: 4096 elems per iteration
__global__ __launch_bounds__(1024) void scan_kernel(const int* __restrict__ counts,
                                                    int* __restrict__ rowptr) {
    __shared__ int wsum[16];
    const int tid = threadIdx.x;
    const int lane = tid & 63;
    const int w = tid >> 6;
    int offset = 0;
    if (tid == 0) rowptr[0] = 0;
    for (int base = 0; base < N_NODES; base += 4096) {
        int i = base + tid * 4;
        int4 v = make_int4(0, 0, 0, 0);
        if (i < N_NODES) v = *reinterpret_cast<const int4*>(counts + i);
        int p0 = v.x, p1 = p0 + v.y, p2 = p1 + v.z, p3 = p2 + v.w;
        int incl = p3;
#pragma unroll
        for (int d = 1; d < 64; d <<= 1) {
            int t = __shfl_up(incl, d, 64);
            if (lane >= d) incl += t;
        }
        if (lane == 63) wsum[w] = incl;
        __syncthreads();
        if (w == 0 && lane < 16) {
            int t = wsum[lane];
#pragma unroll
            for (int d = 1; d < 16; d <<= 1) {
                int u = __shfl_up(t, d, 64);
                if (lane >= d) t += u;
            }
            wsum[lane] = t;
        }
        __syncthreads();
        int woff = (w == 0) ? 0 : wsum[w - 1];
        int chunk_total = wsum[15];
        int tbase = offset + woff + incl - p3;
        if (i < N_NODES) {
            rowptr[i + 1] = tbase + p0;
            rowptr[i + 2] = tbase + p1;
            rowptr[i + 3] = tbase + p2;
            rowptr[i + 4] = tbase + p3;
        }
        offset += chunk_total;
        __syncthreads();
    }
}

// XCD-binned bucket: block handles only dst in its bin -> em lines assembled in one L2
__global__ __launch_bounds__(256) void bucket_kernel(const int* __restrict__ src,
                                                     const int* __restrict__ dst,
                                                     const float* __restrict__ ew,
                                                     const int* __restrict__ rowptr,
                                                     int* __restrict__ fill,
                                                     int2* __restrict__ em) {
    const int myBin = blockIdx.x & (NBINS - 1);
    const int lo = myBin * BINW;
    const int hi = lo + BINW;
    int e = (blockIdx.x >> 3) * 256 + threadIdx.x;
    const int stride = (gridDim.x >> 3) * 256;
    for (; e < N_EDGES; e += stride) {
        int d = dst[e];
        if (d >= lo && d < hi) {
            int pos = atomicAdd(&fill[d], 1);
            em[rowptr[d] + pos] = make_int2(src[e], __float_as_int(ew[e]));
        }
    }
}

// ------- gather aggregation (bf16 H, 128 cols): LDS-broadcast metas, 8 gathers in flight -------
__global__ __launch_bounds__(256) void agg128b_kernel(const unsigned* __restrict__ Hb,
                                                      const int* __restrict__ rowptr,
                                                      const int2* __restrict__ em,
                                                      float* __restrict__ B,
                                                      float* __restrict__ cs_part,
                                                      float* __restrict__ ss_part) {
    __shared__ int2 smeta[4][64];
    __shared__ float cs[4][128];
    __shared__ float ssw[4];
    const int wv = threadIdx.x >> 6;
    const int lane = threadIdx.x & 63;
    const int node = blockIdx.x * 4 + wv;  // grid covers exactly N
    const int beg = rowptr[node];
    const int end = rowptr[node + 1];
    const int2* sm = smeta[wv];
    float ax0 = 0.f, ay0 = 0.f, ax1 = 0.f, ay1 = 0.f;

    for (int c = beg; c < end; c += 64) {
        // stage this chunk's metas into the wave-private LDS strip (zero-padded)
        smeta[wv][lane] = (c + lane < end) ? em[c + lane] : make_int2(0, 0);
        const int cnt = min(64, end - c);
        const int rounds = (cnt + 7) >> 3;
        for (int g = 0; g < rounds; ++g) {
            // 8 wave-uniform broadcast reads (independent), then 8 independent gathers
            int2 m0 = sm[g * 8 + 0];
            int2 m1 = sm[g * 8 + 1];
            int2 m2 = sm[g * 8 + 2];
            int2 m3 = sm[g * 8 + 3];
            int2 m4 = sm[g * 8 + 4];
            int2 m5 = sm[g * 8 + 5];
            int2 m6 = sm[g * 8 + 6];
            int2 m7 = sm[g * 8 + 7];
            unsigned u0 = Hb[(size_t)m0.x * 64 + lane];
            unsigned u1 = Hb[(size_t)m1.x * 64 + lane];
            unsigned u2 = Hb[(size_t)m2.x * 64 + lane];
            unsigned u3 = Hb[(size_t)m3.x * 64 + lane];
            unsigned u4 = Hb[(size_t)m4.x * 64 + lane];
            unsigned u5 = Hb[(size_t)m5.x * 64 + lane];
            unsigned u6 = Hb[(size_t)m6.x * 64 + lane];
            unsigned u7 = Hb[(size_t)m7.x * 64 + lane];
            float w0 = __int_as_float(m0.y), w1 = __int_as_float(m1.y);
            float w2 = __int_as_float(m2.y), w3 = __int_as_float(m3.y);
            float w4 = __int_as_float(m4.y), w5 = __int_as_float(m5.y);
            float w6 = __int_as_float(m6.y), w7 = __int_as_float(m7.y);
            ax0 += w0 * blo(u0); ay0 += w0 * bhi(u0);
            ax1 += w1 * blo(u1); ay1 += w1 * bhi(u1);
            ax0 += w2 * blo(u2); ay0 += w2 * bhi(u2);
            ax1 += w3 * blo(u3); ay1 += w3 * bhi(u3);
            ax0 += w4 * blo(u4); ay0 += w4 * bhi(u4);
            ax1 += w5 * blo(u5); ay1 += w5 * bhi(u5);
            ax0 += w6 * blo(u6); ay0 += w6 * bhi(u6);
            ax1 += w7 * blo(u7); ay1 += w7 * bhi(u7);
        }
    }
    float2 acc = make_float2(ax0 + ax1, ay0 + ay1);
    reinterpret_cast<float2*>(B + (size_t)node * DH)[lane] = acc;

    // fused stats: per-block reduce then replica atomics
    cs[wv][lane * 2] = acc.x;
    cs[wv][lane * 2 + 1] = acc.y;
    float sq = acc.x * acc.x + acc.y * acc.y;
#pragma unroll
    for (int off = 32; off; off >>= 1) sq += __shfl_down(sq, off, 64);
    if (lane == 0) ssw[wv] = sq;
    __syncthreads();
    const int rep = blockIdx.x & (NREP - 1);
    if (threadIdx.x < 128) {
        float s = cs[0][threadIdx.x] + cs[1][threadIdx.x] + cs[2][threadIdx.x] + cs[3][threadIdx.x];
        atomicAdd(&cs_part[rep * 128 + threadIdx.x], s);
    }
    if (threadIdx.x == 0) atomicAdd(&ss_part[rep], ssw[0] + ssw[1] + ssw[2] + ssw[3]);
}

// ------- gather aggregation (bf16 H, 64 cols): LDS metas, 2 edges per wave-load -------
__global__ __launch_bounds__(256) void agg64b_kernel(const unsigned* __restrict__ Hb,
                                                     const int* __restrict__ rowptr,
                                                     const int2* __restrict__ em,
                                                     float* __restrict__ out) {
    __shared__ int2 smeta[4][64];
    const int wv = threadIdx.x >> 6;
    const int lane = threadIdx.x & 63;
    const int half = lane >> 5;  // 0: even edge, 1: odd edge
    const int col = lane & 31;   // bf16-pair index
    const int node = blockIdx.x * 4 + wv;
    const int beg = rowptr[node];
    const int end = rowptr[node + 1];
    const int2* sm = smeta[wv];
    float ax0 = 0.f, ay0 = 0.f, ax1 = 0.f, ay1 = 0.f;

    for (int c = beg; c < end; c += 64) {
        smeta[wv][lane] = (c + lane < end) ? em[c + lane] : make_int2(0, 0);
        const int cnt = min(64, end - c);
        const int rounds = (cnt + 15) >> 4;  // 16 edges per group = 8 paired loads
        for (int g = 0; g < rounds; ++g) {
            const int b = g * 16 + half;
            int2 m0 = sm[b + 0];
            int2 m1 = sm[b + 2];
            int2 m2 = sm[b + 4];
            int2 m3 = sm[b + 6];
            int2 m4 = sm[b + 8];
            int2 m5 = sm[b + 10];
            int2 m6 = sm[b + 12];
            int2 m7 = sm[b + 14];
            unsigned u0 = Hb[(size_t)m0.x * 32 + col];
            unsigned u1 = Hb[(size_t)m1.x * 32 + col];
            unsigned u2 = Hb[(size_t)m2.x * 32 + col];
            unsigned u3 = Hb[(size_t)m3.x * 32 + col];
            unsigned u4 = Hb[(size_t)m4.x * 32 + col];
            unsigned u5 = Hb[(size_t)m5.x * 32 + col];
            unsigned u6 = Hb[(size_t)m6.x * 32 + col];
            unsigned u7 = Hb[(size_t)m7.x * 32 + col];
            float w0 = __int_as_float(m0.y), w1 = __int_as_float(m1.y);
            float w2 = __int_as_float(m2.y), w3 = __int_as_float(m3.y);
            float w4 = __int_as_float(m4.y), w5 = __int_as_float(m5.y);
            float w6 = __int_as_float(m6.y), w7 = __int_as_float(m7.y);
            ax0 += w0 * blo(u0); ay0 += w0 * bhi(u0);
            ax1 += w1 * blo(u1); ay1 += w1 * bhi(u1);
            ax0 += w2 * blo(u2); ay0 += w2 * bhi(u2);
            ax1 += w3 * blo(u3); ay1 += w3 * bhi(u3);
            ax0 += w4 * blo(u4); ay0 += w4 * bhi(u4);
            ax1 += w5 * blo(u5); ay1 += w5 * bhi(u5);
            ax0 += w6 * blo(u6); ay0 += w6 * bhi(u6);
            ax1 += w7 * blo(u7); ay1 += w7 * bhi(u7);
        }
    }
    float ax = ax0 + ax1, ay = ay0 + ay1;
    ax += __shfl_xor(ax, 32, 64);  // combine even/odd edge halves
    ay += __shfl_xor(ay, 32, 64);
    if (lane < 32) {
        reinterpret_cast<float2*>(out + (size_t)node * DOUT)[col] = make_float2(ax, ay);
    }
}

// ---------------- finalize: reduce replicas -> mu, inv ----------------
__global__ void finalize_stats(const float* __restrict__ cs_part,
                               const float* __restrict__ ss_part, float* __restrict__ mu,
                               float* __restrict__ inv) {
    const int t = threadIdx.x;  // 128 threads
    float m = 0.f;
    for (int r = 0; r < NREP; ++r) m += cs_part[r * 128 + t];
    float mean = m / (float)N_NODES;
    mu[t] = mean;
    float v = mean * mean;
    __shared__ float partl[2];
    __shared__ float sstot;
#pragma unroll
    for (int off = 32; off; off >>= 1) v += __shfl_down(v, off, 64);
    if ((t & 63) == 0) partl[t >> 6] = v;
    float ss = (t < NREP) ? ss_part[t] : 0.f;
#pragma unroll
    for (int off = 32; off; off >>= 1) ss += __shfl_down(ss, off, 64);
    if (t == 0) sstot = ss;
    __syncthreads();
    if (t == 0) {
        float musq = partl[0] + partl[1];
        float s = (sstot - (float)N_NODES * musq) / (float)N_NODES;
        inv[0] = rsqrtf(EPS + s);
    }
}

extern "C" void kernel_launch(void* const* d_in, const int* in_sizes, int n_in,
                              void* d_out, int out_size, void* d_ws, size_t ws_size,
                              hipStream_t stream) {
    const float* x = (const float*)d_in[0];
    const int* edge_index = (const int*)d_in[1];
    const float* ew = (const float*)d_in[2];
    const float* W0 = (const float*)d_in[3];
    const float* b0 = (const float*)d_in[4];
    const float* W1 = (const float*)d_in[5];
    const float* b1 = (const float*)d_in[6];
    const float* Wout = (const float*)d_in[7];
    const float* bout = (const float*)d_in[8];

    const int* src = edge_index;
    const int* dst = edge_index + N_EDGES;
    float* out = (float*)d_out;

    // workspace layout
    float* base = (float*)d_ws;
    unsigned* Hb = (unsigned*)base;                 // bf16 H: uint[N][64]; HOUT aliases uint[N][32]
    float* B1 = base + (size_t)N_NODES * 64;        // N*128 row-major f32
    float* B2 = B1 + (size_t)N_NODES * DH;          // N*128 row-major f32
    int2* em = (int2*)(B2 + (size_t)N_NODES * DH);  // E int2
    int* counts = (int*)(em + N_EDGES);             // N
    int* fill = counts + N_NODES;                   // N
    int* rowptr = fill + N_NODES;                   // N+1
    size_t soff = (size_t)(rowptr + N_NODES + 1 - (int*)base);
    soff = (soff + 3) & ~(size_t)3;
    float* stats = base + soff;
    float* cs_part1 = stats;                  // NREP*128
    float* ss_part1 = cs_part1 + NREP * 128;  // NREP
    float* cs_part2 = ss_part1 + NREP;        // NREP*128
    float* ss_part2 = cs_part2 + NREP * 128;  // NREP
    float* mu1 = ss_part2 + NREP;             // 128
    float* inv1 = mu1 + 128;                  // 1 (+3 pad)
    float* mu2 = inv1 + 4;                    // 128
    float* inv2 = mu2 + 128;                  // 1

    const int gemm_grid = (N_NODES + 63) / 64;
    const int agg_grid = N_NODES / 4;  // 25000 exact

    // zero init
    hipMemsetAsync(counts, 0, (size_t)2 * N_NODES * sizeof(int), stream);  // counts + fill
    hipMemsetAsync(stats, 0, (size_t)2 * (NREP * 128 + NREP) * sizeof(float), stream);

    // CSR build (dst-ordered)
    hist_kernel<<<2048, 256, 0, stream>>>(dst, counts);
    scan_kernel<<<1, 1024, 0, stream>>>(counts, rowptr);
    bucket_kernel<<<2048, 256, 0, stream>>>(src, dst, ew, rowptr, fill, em);

    // Layer 1
    gemm_kernel<128, 0, true><<<gemm_grid, 256, 0, stream>>>(
        x, nullptr, nullptr, nullptr, nullptr, nullptr, W0, b0, Hb, N_NODES);
    agg128b_kernel<<<agg_grid, 256, 0, stream>>>(Hb, rowptr, em, B1, cs_part1, ss_part1);
    finalize_stats<<<1, 128, 0, stream>>>(cs_part1, ss_part1, mu1, inv1);

    // Layer 2
    gemm_kernel<128, 1, true><<<gemm_grid, 256, 0, stream>>>(
        B1, mu1, inv1, nullptr, nullptr, nullptr, W1, b1, Hb, N_NODES);
    agg128b_kernel<<<agg_grid, 256, 0, stream>>>(Hb, rowptr, em, B2, cs_part2, ss_part2);
    finalize_stats<<<1, 128, 0, stream>>>(cs_part2, ss_part2, mu2, inv2);

    // Output layer: HOUT(bf16) = (relu(pn2(B2))+relu(pn1(B1)))@Wout+bout; out = gather
    gemm_kernel<64, 2, true><<<gemm_grid, 256, 0, stream>>>(
        B2, mu2, inv2, B1, mu1, inv1, Wout, bout, Hb, N_NODES);
    agg64b_kernel<<<agg_grid, 256, 0, stream>>>(Hb, rowptr, em, out);
}

// Round 9
// 556.749 us; speedup vs baseline: 2.2784x; 1.0595x over previous
//
#include <hip/hip_runtime.h>

#define N_NODES 100000
#define N_EDGES 1600000
#define DH 128
#define DOUT 64
#define EPS 1e-6f
#define NBINS 8
#define BINW 12500  // ceil(N_NODES / NBINS)
#define NREP 64     // stats replica buffers

typedef __attribute__((ext_vector_type(8))) short s8v;    // 8 bf16 (4 VGPRs)
typedef __attribute__((ext_vector_type(4))) float f32x4;  // MFMA accumulator

__device__ inline unsigned bfround(float f) {  // f32 -> bf16 bits, round-nearest-even
    unsigned u = __float_as_uint(f);
    return (u + 0x7fffu + ((u >> 16) & 1u)) >> 16;
}
__device__ inline unsigned pack2(float a, float b) { return bfround(a) | (bfround(b) << 16); }
__device__ inline float blo(unsigned u) { return __uint_as_float(u << 16); }
__device__ inline float bhi(unsigned u) { return __uint_as_float(u & 0xffff0000u); }

// ------------- MFMA GEMM: Y(bf16)[nrows,COLS] = f(X)[nrows,128] @ W[128,COLS] + b -------------
// PN=0: f(X)=Xa.  PN=1: f(X)=relu((Xa-muA)*invA).  PN=2: ...+relu((Xb-muB)*invB)
// Block tile: 128 rows (2 sub-tiles of 64), 4 waves; wave w owns rows 16w..16w+15 of sub-tile.
// LDS: wtu[c][k-pair] and xbu[r][k-pair], both XOR-swizzled (u ^= (row&7)<<2) per G4.
template <int COLS, int PN>
__global__ __launch_bounds__(256) void gemm_mfma(const float* __restrict__ Xa,
                                                 const float* __restrict__ muA,
                                                 const float* __restrict__ invA,
                                                 const float* __restrict__ Xb,
                                                 const float* __restrict__ muB,
                                                 const float* __restrict__ invB,
                                                 const float* __restrict__ W,
                                                 const float* __restrict__ bias,
                                                 unsigned* __restrict__ Y, int nrows) {
    constexpr int CT = COLS / 16;  // col tiles per wave
    __shared__ unsigned wtu[COLS][64];  // W^T bf16 pairs: [c][k/2], swizzled
    __shared__ unsigned xbu[64][64];    // X bf16 pairs:   [r][k/2], swizzled

    const int tid = threadIdx.x;
    const int wv = tid >> 6;
    const int lane = tid & 63;
    const float sA = (PN >= 1) ? invA[0] : 0.f;
    const float sB = (PN == 2) ? invB[0] : 0.f;

    // ---- stage W^T as bf16 (once per block) ----
    {
        ushort* wts = (ushort*)wtu;
        constexpr int NV4 = 128 * COLS / 4;
        for (int i = tid; i < NV4; i += 256) {
            int k = i / (COLS / 4);
            int c4 = i % (COLS / 4);
            float4 w4 = reinterpret_cast<const float4*>(W)[i];
            float vals[4] = {w4.x, w4.y, w4.z, w4.w};
            int u = k >> 1, kb = k & 1;
#pragma unroll
            for (int j = 0; j < 4; ++j) {
                int c = c4 * 4 + j;
                int us = u ^ ((c & 7) << 2);
                wts[c * 128 + us * 2 + kb] = (ushort)bfround(vals[j]);
            }
        }
    }

    float bv[CT];
#pragma unroll
    for (int f = 0; f < CT; ++f) bv[f] = bias[f * 16 + (lane & 15)];

    const int row0 = blockIdx.x * 128;
    const int myr = (wv << 4) + (lane & 15);  // this lane's A-row within the 64-row sub-tile

#pragma unroll
    for (int ms = 0; ms < 2; ++ms) {
        const int rb = row0 + ms * 64;
        __syncthreads();  // xbu safe to overwrite; also orders wtu staging before first use
        // ---- stage X sub-tile (64 x 128) with fused PN, as bf16 ----
        for (int i = tid; i < 2048; i += 256) {
            int r = i >> 5;
            int c4 = i & 31;
            float4 v = make_float4(0.f, 0.f, 0.f, 0.f);
            if (rb + r < nrows) {
                v = reinterpret_cast<const float4*>(Xa + (size_t)(rb + r) * 128)[c4];
                if constexpr (PN >= 1) {
                    float4 m = reinterpret_cast<const float4*>(muA)[c4];
                    v.x = fmaxf((v.x - m.x) * sA, 0.f);
                    v.y = fmaxf((v.y - m.y) * sA, 0.f);
                    v.z = fmaxf((v.z - m.z) * sA, 0.f);
                    v.w = fmaxf((v.w - m.w) * sA, 0.f);
                }
                if constexpr (PN == 2) {
                    float4 v2 = reinterpret_cast<const float4*>(Xb + (size_t)(rb + r) * 128)[c4];
                    float4 m2 = reinterpret_cast<const float4*>(muB)[c4];
                    v.x += fmaxf((v2.x - m2.x) * sB, 0.f);
                    v.y += fmaxf((v2.y - m2.y) * sB, 0.f);
                    v.z += fmaxf((v2.z - m2.z) * sB, 0.f);
                    v.w += fmaxf((v2.w - m2.w) * sB, 0.f);
                }
            }
            int sw = (r & 7) << 2;
            xbu[r][(c4 * 2) ^ sw] = pack2(v.x, v.y);
            xbu[r][(c4 * 2 + 1) ^ sw] = pack2(v.z, v.w);
        }
        __syncthreads();

        // ---- MFMA: 4 K-chunks of 32 ----
        f32x4 acc[CT];
#pragma unroll
        for (int f = 0; f < CT; ++f) acc[f] = (f32x4){0.f, 0.f, 0.f, 0.f};
        const int xsw = (myr & 7) << 2;
#pragma unroll
        for (int kc = 0; kc < 4; ++kc) {
            const int u0 = kc * 16 + (lane >> 4) * 4;
            s8v a = *reinterpret_cast<const s8v*>(&xbu[myr][u0 ^ xsw]);
#pragma unroll
            for (int f = 0; f < CT; ++f) {
                const int c = f * 16 + (lane & 15);
                s8v b = *reinterpret_cast<const s8v*>(&wtu[c][u0 ^ ((c & 7) << 2)]);
                acc[f] = __builtin_amdgcn_mfma_f32_16x16x32_bf16(a, b, acc[f], 0, 0, 0);
            }
        }

        // ---- epilogue: bias, pack bf16 pairs via shfl_xor(1), store ----
#pragma unroll
        for (int f = 0; f < CT; ++f) {
#pragma unroll
            for (int r = 0; r < 4; ++r) {
                float v = acc[f][r] + bv[f];
                float p = __shfl_xor(v, 1, 64);
                unsigned pk = (lane & 1) ? pack2(p, v) : pack2(v, p);
                int grow = rb + (wv << 4) + ((lane >> 4) << 2) + r;
                if (grow < nrows && ((lane & 1) == (f & 1))) {
                    Y[(size_t)grow * (COLS / 2) + f * 8 + ((lane & 15) >> 1)] = pk;
                }
            }
        }
    }
}

// ---------------- CSR build ----------------
__global__ __launch_bounds__(256) void hist_kernel(const int* __restrict__ dst,
                                                   int* __restrict__ counts) {
    int i = blockIdx.x * blockDim.x + threadIdx.x;
    const int stride = gridDim.x * blockDim.x;
    for (; i < N_EDGES / 4; i += stride) {
        int4 d = reinterpret_cast<const int4*>(dst)[i];
        atomicAdd(&counts[d.x], 1);
        atomicAdd(&counts[d.y], 1);
        atomicAdd(&counts[d.z], 1);
        atomicAdd(&counts[d.w], 1);
    }
}

// single-block scan, int4-widened: 4096 elems per iteration
__global__ __launch_bounds__(1024) void scan_kernel(const int* __restrict__ counts,
                                                    int* __restrict__ rowptr) {
    __shared__ int wsum[16];
    const int tid = threadIdx.x;
    const int lane = tid & 63;
    const int w = tid >> 6;
    int offset = 0;
    if (tid == 0) rowptr[0] = 0;
    for (int base = 0; base < N_NODES; base += 4096) {
        int i = base + tid * 4;
        int4 v = make_int4(0, 0, 0, 0);
        if (i < N_NODES) v = *reinterpret_cast<const int4*>(counts + i);
        int p0 = v.x, p1 = p0 + v.y, p2 = p1 + v.z, p3 = p2 + v.w;
        int incl = p3;
#pragma unroll
        for (int d = 1; d < 64; d <<= 1) {
            int t = __shfl_up(incl, d, 64);
            if (lane >= d) incl += t;
        }
        if (lane == 63) wsum[w] = incl;
        __syncthreads();
        if (w == 0 && lane < 16) {
            int t = wsum[lane];
#pragma unroll
            for (int d = 1; d < 16; d <<= 1) {
                int u = __shfl_up(t, d, 64);
                if (lane >= d) t += u;
            }
            wsum[lane] = t;
        }
        __syncthreads();
        int woff = (w == 0) ? 0 : wsum[w - 1];
        int chunk_total = wsum[15];
        int tbase = offset + woff + incl - p3;
        if (i < N_NODES) {
            rowptr[i + 1] = tbase + p0;
            rowptr[i + 2] = tbase + p1;
            rowptr[i + 3] = tbase + p2;
            rowptr[i + 4] = tbase + p3;
        }
        offset += chunk_total;
        __syncthreads();
    }
}

// XCD-binned bucket: block handles only dst in its bin -> em lines assembled in one L2
__global__ __launch_bounds__(256) void bucket_kernel(const int* __restrict__ src,
                                                     const int* __restrict__ dst,
                                                     const float* __restrict__ ew,
                                                     const int* __restrict__ rowptr,
                                                     int* __restrict__ fill,
                                                     int2* __restrict__ em) {
    const int myBin = blockIdx.x & (NBINS - 1);
    const int lo = myBin * BINW;
    const int hi = lo + BINW;
    int e = (blockIdx.x >> 3) * 256 + threadIdx.x;
    const int stride = (gridDim.x >> 3) * 256;
    for (; e < N_EDGES; e += stride) {
        int d = dst[e];
        if (d >= lo && d < hi) {
            int pos = atomicAdd(&fill[d], 1);
            em[rowptr[d] + pos] = make_int2(src[e], __float_as_int(ew[e]));
        }
    }
}

// ------- gather aggregation (bf16 H, 128 cols): LDS-broadcast metas, 8 gathers in flight -------
__global__ __launch_bounds__(256) void agg128b_kernel(const unsigned* __restrict__ Hb,
                                                      const int* __restrict__ rowptr,
                                                      const int2* __restrict__ em,
                                                      float* __restrict__ B,
                                                      float* __restrict__ cs_part,
                                                      float* __restrict__ ss_part) {
    __shared__ int2 smeta[4][64];
    __shared__ float cs[4][128];
    __shared__ float ssw[4];
    const int wv = threadIdx.x >> 6;
    const int lane = threadIdx.x & 63;
    const int node = blockIdx.x * 4 + wv;  // grid covers exactly N
    const int beg = rowptr[node];
    const int end = rowptr[node + 1];
    const int2* sm = smeta[wv];
    float ax0 = 0.f, ay0 = 0.f, ax1 = 0.f, ay1 = 0.f;

    for (int c = beg; c < end; c += 64) {
        smeta[wv][lane] = (c + lane < end) ? em[c + lane] : make_int2(0, 0);
        const int cnt = min(64, end - c);
        const int rounds = (cnt + 7) >> 3;
        for (int g = 0; g < rounds; ++g) {
            int2 m0 = sm[g * 8 + 0];
            int2 m1 = sm[g * 8 + 1];
            int2 m2 = sm[g * 8 + 2];
            int2 m3 = sm[g * 8 + 3];
            int2 m4 = sm[g * 8 + 4];
            int2 m5 = sm[g * 8 + 5];
            int2 m6 = sm[g * 8 + 6];
            int2 m7 = sm[g * 8 + 7];
            unsigned u0 = Hb[(size_t)m0.x * 64 + lane];
            unsigned u1 = Hb[(size_t)m1.x * 64 + lane];
            unsigned u2 = Hb[(size_t)m2.x * 64 + lane];
            unsigned u3 = Hb[(size_t)m3.x * 64 + lane];
            unsigned u4 = Hb[(size_t)m4.x * 64 + lane];
            unsigned u5 = Hb[(size_t)m5.x * 64 + lane];
            unsigned u6 = Hb[(size_t)m6.x * 64 + lane];
            unsigned u7 = Hb[(size_t)m7.x * 64 + lane];
            float w0 = __int_as_float(m0.y), w1 = __int_as_float(m1.y);
            float w2 = __int_as_float(m2.y), w3 = __int_as_float(m3.y);
            float w4 = __int_as_float(m4.y), w5 = __int_as_float(m5.y);
            float w6 = __int_as_float(m6.y), w7 = __int_as_float(m7.y);
            ax0 += w0 * blo(u0); ay0 += w0 * bhi(u0);
            ax1 += w1 * blo(u1); ay1 += w1 * bhi(u1);
            ax0 += w2 * blo(u2); ay0 += w2 * bhi(u2);
            ax1 += w3 * blo(u3); ay1 += w3 * bhi(u3);
            ax0 += w4 * blo(u4); ay0 += w4 * bhi(u4);
            ax1 += w5 * blo(u5); ay1 += w5 * bhi(u5);
            ax0 += w6 * blo(u6); ay0 += w6 * bhi(u6);
            ax1 += w7 * blo(u7); ay1 += w7 * bhi(u7);
        }
    }
    float2 acc = make_float2(ax0 + ax1, ay0 + ay1);
    reinterpret_cast<float2*>(B + (size_t)node * DH)[lane] = acc;

    cs[wv][lane * 2] = acc.x;
    cs[wv][lane * 2 + 1] = acc.y;
    float sq = acc.x * acc.x + acc.y * acc.y;
#pragma unroll
    for (int off = 32; off; off >>= 1) sq += __shfl_down(sq, off, 64);
    if (lane == 0) ssw[wv] = sq;
    __syncthreads();
    const int rep = blockIdx.x & (NREP - 1);
    if (threadIdx.x < 128) {
        float s = cs[0][threadIdx.x] + cs[1][threadIdx.x] + cs[2][threadIdx.x] + cs[3][threadIdx.x];
        atomicAdd(&cs_part[rep * 128 + threadIdx.x], s);
    }
    if (threadIdx.x == 0) atomicAdd(&ss_part[rep], ssw[0] + ssw[1] + ssw[2] + ssw[3]);
}

// ------- gather aggregation (bf16 H, 64 cols): LDS metas, 2 edges per wave-load -------
__global__ __launch_bounds__(256) void agg64b_kernel(const unsigned* __restrict__ Hb,
                                                     const int* __restrict__ rowptr,
                                                     const int2* __restrict__ em,
                                                     float* __restrict__ out) {
    __shared__ int2 smeta[4][64];
    const int wv = threadIdx.x >> 6;
    const int lane = threadIdx.x & 63;
    const int half = lane >> 5;
    const int col = lane & 31;
    const int node = blockIdx.x * 4 + wv;
    const int beg = rowptr[node];
    const int end = rowptr[node + 1];
    const int2* sm = smeta[wv];
    float ax0 = 0.f, ay0 = 0.f, ax1 = 0.f, ay1 = 0.f;

    for (int c = beg; c < end; c += 64) {
        smeta[wv][lane] = (c + lane < end) ? em[c + lane] : make_int2(0, 0);
        const int cnt = min(64, end - c);
        const int rounds = (cnt + 15) >> 4;
        for (int g = 0; g < rounds; ++g) {
            const int b = g * 16 + half;
            int2 m0 = sm[b + 0];
            int2 m1 = sm[b + 2];
            int2 m2 = sm[b + 4];
            int2 m3 = sm[b + 6];
            int2 m4 = sm[b + 8];
            int2 m5 = sm[b + 10];
            int2 m6 = sm[b + 12];
            int2 m7 = sm[b + 14];
            unsigned u0 = Hb[(size_t)m0.x * 32 + col];
            unsigned u1 = Hb[(size_t)m1.x * 32 + col];
            unsigned u2 = Hb[(size_t)m2.x * 32 + col];
            unsigned u3 = Hb[(size_t)m3.x * 32 + col];
            unsigned u4 = Hb[(size_t)m4.x * 32 + col];
            unsigned u5 = Hb[(size_t)m5.x * 32 + col];
            unsigned u6 = Hb[(size_t)m6.x * 32 + col];
            unsigned u7 = Hb[(size_t)m7.x * 32 + col];
            float w0 = __int_as_float(m0.y), w1 = __int_as_float(m1.y);
            float w2 = __int_as_float(m2.y), w3 = __int_as_float(m3.y);
            float w4 = __int_as_float(m4.y), w5 = __int_as_float(m5.y);
            float w6 = __int_as_float(m6.y), w7 = __int_as_float(m7.y);
            ax0 += w0 * blo(u0); ay0 += w0 * bhi(u0);
            ax1 += w1 * blo(u1); ay1 += w1 * bhi(u1);
            ax0 += w2 * blo(u2); ay0 += w2 * bhi(u2);
            ax1 += w3 * blo(u3); ay1 += w3 * bhi(u3);
            ax0 += w4 * blo(u4); ay0 += w4 * bhi(u4);
            ax1 += w5 * blo(u5); ay1 += w5 * bhi(u5);
            ax0 += w6 * blo(u6); ay0 += w6 * bhi(u6);
            ax1 += w7 * blo(u7); ay1 += w7 * bhi(u7);
        }
    }
    float ax = ax0 + ax1, ay = ay0 + ay1;
    ax += __shfl_xor(ax, 32, 64);
    ay += __shfl_xor(ay, 32, 64);
    if (lane < 32) {
        reinterpret_cast<float2*>(out + (size_t)node * DOUT)[col] = make_float2(ax, ay);
    }
}

// ---------------- finalize: reduce replicas -> mu, inv ----------------
__global__ void finalize_stats(const float* __restrict__ cs_part,
                               const float* __restrict__ ss_part, float* __restrict__ mu,
                               float* __restrict__ inv) {
    const int t = threadIdx.x;  // 128 threads
    float m = 0.f;
    for (int r = 0; r < NREP; ++r) m += cs_part[r * 128 + t];
    float mean = m / (float)N_NODES;
    mu[t] = mean;
    float v = mean * mean;
    __shared__ float partl[2];
    __shared__ float sstot;
#pragma unroll
    for (int off = 32; off; off >>= 1) v += __shfl_down(v, off, 64);
    if ((t & 63) == 0) partl[t >> 6] = v;
    float ss = (t < NREP) ? ss_part[t] : 0.f;
#pragma unroll
    for (int off = 32; off; off >>= 1) ss += __shfl_down(ss, off, 64);
    if (t == 0) sstot = ss;
    __syncthreads();
    if (t == 0) {
        float musq = partl[0] + partl[1];
        float s = (sstot - (float)N_NODES * musq) / (float)N_NODES;
        inv[0] = rsqrtf(EPS + s);
    }
}

extern "C" void kernel_launch(void* const* d_in, const int* in_sizes, int n_in,
                              void* d_out, int out_size, void* d_ws, size_t ws_size,
                              hipStream_t stream) {
    const float* x = (const float*)d_in[0];
    const int* edge_index = (const int*)d_in[1];
    const float* ew = (const float*)d_in[2];
    const float* W0 = (const float*)d_in[3];
    const float* b0 = (const float*)d_in[4];
    const float* W1 = (const float*)d_in[5];
    const float* b1 = (const float*)d_in[6];
    const float* Wout = (const float*)d_in[7];
    const float* bout = (const float*)d_in[8];

    const int* src = edge_index;
    const int* dst = edge_index + N_EDGES;
    float* out = (float*)d_out;

    // workspace layout
    float* base = (float*)d_ws;
    unsigned* Hb = (unsigned*)base;                 // bf16 H: uint[N][64]; HOUT aliases uint[N][32]
    float* B1 = base + (size_t)N_NODES * 64;        // N*128 row-major f32
    float* B2 = B1 + (size_t)N_NODES * DH;          // N*128 row-major f32
    int2* em = (int2*)(B2 + (size_t)N_NODES * DH);  // E int2
    int* counts = (int*)(em + N_EDGES);             // N
    int* fill = counts + N_NODES;                   // N
    int* rowptr = fill + N_NODES;                   // N+1
    size_t soff = (size_t)(rowptr + N_NODES + 1 - (int*)base);
    soff = (soff + 3) & ~(size_t)3;
    float* stats = base + soff;
    float* cs_part1 = stats;                  // NREP*128
    float* ss_part1 = cs_part1 + NREP * 128;  // NREP
    float* cs_part2 = ss_part1 + NREP;        // NREP*128
    float* ss_part2 = cs_part2 + NREP * 128;  // NREP
    float* mu1 = ss_part2 + NREP;             // 128
    float* inv1 = mu1 + 128;                  // 1 (+3 pad)
    float* mu2 = inv1 + 4;                    // 128
    float* inv2 = mu2 + 128;                  // 1

    const int gemm_grid = (N_NODES + 127) / 128;  // 782
    const int agg_grid = N_NODES / 4;             // 25000 exact

    // zero init
    hipMemsetAsync(counts, 0, (size_t)2 * N_NODES * sizeof(int), stream);  // counts + fill
    hipMemsetAsync(stats, 0, (size_t)2 * (NREP * 128 + NREP) * sizeof(float), stream);

    // CSR build (dst-ordered)
    hist_kernel<<<1024, 256, 0, stream>>>(dst, counts);
    scan_kernel<<<1, 1024, 0, stream>>>(counts, rowptr);
    bucket_kernel<<<2048, 256, 0, stream>>>(src, dst, ew, rowptr, fill, em);

    // Layer 1
    gemm_mfma<128, 0><<<gemm_grid, 256, 0, stream>>>(
        x, nullptr, nullptr, nullptr, nullptr, nullptr, W0, b0, Hb, N_NODES);
    agg128b_kernel<<<agg_grid, 256, 0, stream>>>(Hb, rowptr, em, B1, cs_part1, ss_part1);
    finalize_stats<<<1, 128, 0, stream>>>(cs_part1, ss_part1, mu1, inv1);

    // Layer 2
    gemm_mfma<128, 1><<<gemm_grid, 256, 0, stream>>>(
        B1, mu1, inv1, nullptr, nullptr, nullptr, W1, b1, Hb, N_NODES);
    agg128b_kernel<<<agg_grid, 256, 0, stream>>>(Hb, rowptr, em, B2, cs_part2, ss_part2);
    finalize_stats<<<1, 128, 0, stream>>>(cs_part2, ss_part2, mu2, inv2);

    // Output layer: HOUT(bf16) = (relu(pn2(B2))+relu(pn1(B1)))@Wout+bout; out = gather
    gemm_mfma<64, 2><<<gemm_grid, 256, 0, stream>>>(
        B2, mu2, inv2, B1, mu1, inv1, Wout, bout, Hb, N_NODES);
    agg64b_kernel<<<agg_grid, 256, 0, stream>>>(Hb, rowptr, em, out);
}

// Round 10
// 539.386 us; speedup vs baseline: 2.3518x; 1.0322x over previous
//
#include <hip/hip_runtime.h>

#define N_NODES 100000
#define N_EDGES 1600000
#define DH 128
#define DOUT 64
#define EPS 1e-6f
#define NBINS 8
#define BINW 12500  // ceil(N_NODES / NBINS)
#define NREP 64     // stats replica buffers

typedef __attribute__((ext_vector_type(8))) short s8v;    // 8 bf16 (4 VGPRs)
typedef __attribute__((ext_vector_type(4))) float f32x4;  // MFMA accumulator

__device__ inline unsigned bfround(float f) {  // f32 -> bf16 bits, round-nearest-even
    unsigned u = __float_as_uint(f);
    return (u + 0x7fffu + ((u >> 16) & 1u)) >> 16;
}
__device__ inline unsigned pack2(float a, float b) { return bfround(a) | (bfround(b) << 16); }
__device__ inline float blo(unsigned u) { return __uint_as_float(u << 16); }
__device__ inline float bhi(unsigned u) { return __uint_as_float(u & 0xffff0000u); }

// ------------- MFMA GEMM: Y(bf16)[nrows,COLS] = f(X)[nrows,128] @ W[128,COLS] + b -------------
// PN=0: X is f32, f(X)=X.  PN=1: X bf16, f=relu((X-muA)*invA).  PN=2: + relu((Xb-muB)*invB)
template <int COLS, int PN>
__global__ __launch_bounds__(256) void gemm_mfma(const void* __restrict__ Xav,
                                                 const float* __restrict__ muA,
                                                 const float* __restrict__ invA,
                                                 const unsigned* __restrict__ Xbu2,
                                                 const float* __restrict__ muB,
                                                 const float* __restrict__ invB,
                                                 const float* __restrict__ W,
                                                 const float* __restrict__ bias,
                                                 unsigned* __restrict__ Y, int nrows) {
    constexpr int CT = COLS / 16;       // col tiles per wave
    __shared__ unsigned wtu[COLS][64];  // W^T bf16 pairs: [c][k/2], swizzled
    __shared__ unsigned xbu[64][64];    // X bf16 pairs:   [r][k/2], swizzled

    const int tid = threadIdx.x;
    const int wv = tid >> 6;
    const int lane = tid & 63;
    const float sA = (PN >= 1) ? invA[0] : 0.f;
    const float sB = (PN == 2) ? invB[0] : 0.f;

    // ---- stage W^T as bf16 (once per block) ----
    {
        ushort* wts = (ushort*)wtu;
        constexpr int NV4 = 128 * COLS / 4;
        for (int i = tid; i < NV4; i += 256) {
            int k = i / (COLS / 4);
            int c4 = i % (COLS / 4);
            float4 w4 = reinterpret_cast<const float4*>(W)[i];
            float vals[4] = {w4.x, w4.y, w4.z, w4.w};
            int u = k >> 1, kb = k & 1;
#pragma unroll
            for (int j = 0; j < 4; ++j) {
                int c = c4 * 4 + j;
                int us = u ^ ((c & 7) << 2);
                wts[c * 128 + us * 2 + kb] = (ushort)bfround(vals[j]);
            }
        }
    }

    float bv[CT];
#pragma unroll
    for (int f = 0; f < CT; ++f) bv[f] = bias[f * 16 + (lane & 15)];

    const int row0 = blockIdx.x * 128;
    const int myr = (wv << 4) + (lane & 15);

#pragma unroll
    for (int ms = 0; ms < 2; ++ms) {
        const int rb = row0 + ms * 64;
        __syncthreads();  // xbu safe to overwrite; orders wtu staging before first use
        if constexpr (PN == 0) {
            const float* Xa = (const float*)Xav;
            for (int i = tid; i < 2048; i += 256) {
                int r = i >> 5;
                int c4 = i & 31;
                float4 v = make_float4(0.f, 0.f, 0.f, 0.f);
                if (rb + r < nrows) v = reinterpret_cast<const float4*>(Xa + (size_t)(rb + r) * 128)[c4];
                int sw = (r & 7) << 2;
                xbu[r][(c4 * 2) ^ sw] = pack2(v.x, v.y);
                xbu[r][(c4 * 2 + 1) ^ sw] = pack2(v.z, v.w);
            }
        } else {
            const unsigned* Xa = (const unsigned*)Xav;
            for (int i = tid; i < 1024; i += 256) {
                int r = i >> 4;
                int c4 = i & 15;  // uint4 index: uints 4c4..4c4+3 = cols 8c4..8c4+7
                float v0 = 0.f, v1 = 0.f, v2 = 0.f, v3 = 0.f, v4 = 0.f, v5 = 0.f, v6 = 0.f,
                      v7 = 0.f;
                if (rb + r < nrows) {
                    uint4 uv = reinterpret_cast<const uint4*>(Xa + (size_t)(rb + r) * 64)[c4];
                    float4 ma = reinterpret_cast<const float4*>(muA)[c4 * 2];
                    float4 mb = reinterpret_cast<const float4*>(muA)[c4 * 2 + 1];
                    v0 = fmaxf((blo(uv.x) - ma.x) * sA, 0.f);
                    v1 = fmaxf((bhi(uv.x) - ma.y) * sA, 0.f);
                    v2 = fmaxf((blo(uv.y) - ma.z) * sA, 0.f);
                    v3 = fmaxf((bhi(uv.y) - ma.w) * sA, 0.f);
                    v4 = fmaxf((blo(uv.z) - mb.x) * sA, 0.f);
                    v5 = fmaxf((bhi(uv.z) - mb.y) * sA, 0.f);
                    v6 = fmaxf((blo(uv.w) - mb.z) * sA, 0.f);
                    v7 = fmaxf((bhi(uv.w) - mb.w) * sA, 0.f);
                    if constexpr (PN == 2) {
                        uint4 u2 = reinterpret_cast<const uint4*>(Xbu2 + (size_t)(rb + r) * 64)[c4];
                        float4 na = reinterpret_cast<const float4*>(muB)[c4 * 2];
                        float4 nb = reinterpret_cast<const float4*>(muB)[c4 * 2 + 1];
                        v0 += fmaxf((blo(u2.x) - na.x) * sB, 0.f);
                        v1 += fmaxf((bhi(u2.x) - na.y) * sB, 0.f);
                        v2 += fmaxf((blo(u2.y) - na.z) * sB, 0.f);
                        v3 += fmaxf((bhi(u2.y) - na.w) * sB, 0.f);
                        v4 += fmaxf((blo(u2.z) - nb.x) * sB, 0.f);
                        v5 += fmaxf((bhi(u2.z) - nb.y) * sB, 0.f);
                        v6 += fmaxf((blo(u2.w) - nb.z) * sB, 0.f);
                        v7 += fmaxf((bhi(u2.w) - nb.w) * sB, 0.f);
                    }
                }
                int sw = (r & 7) << 2;
                xbu[r][(c4 * 4 + 0) ^ sw] = pack2(v0, v1);
                xbu[r][(c4 * 4 + 1) ^ sw] = pack2(v2, v3);
                xbu[r][(c4 * 4 + 2) ^ sw] = pack2(v4, v5);
                xbu[r][(c4 * 4 + 3) ^ sw] = pack2(v6, v7);
            }
        }
        __syncthreads();

        // ---- MFMA: 4 K-chunks of 32 ----
        f32x4 acc[CT];
#pragma unroll
        for (int f = 0; f < CT; ++f) acc[f] = (f32x4){0.f, 0.f, 0.f, 0.f};
        const int xsw = (myr & 7) << 2;
#pragma unroll
        for (int kc = 0; kc < 4; ++kc) {
            const int u0 = kc * 16 + (lane >> 4) * 4;
            s8v a = *reinterpret_cast<const s8v*>(&xbu[myr][u0 ^ xsw]);
#pragma unroll
            for (int f = 0; f < CT; ++f) {
                const int c = f * 16 + (lane & 15);
                s8v b = *reinterpret_cast<const s8v*>(&wtu[c][u0 ^ ((c & 7) << 2)]);
                acc[f] = __builtin_amdgcn_mfma_f32_16x16x32_bf16(a, b, acc[f], 0, 0, 0);
            }
        }

        // ---- epilogue: bias, pack bf16 pairs via shfl_xor(1), store ----
#pragma unroll
        for (int f = 0; f < CT; ++f) {
#pragma unroll
            for (int r = 0; r < 4; ++r) {
                float v = acc[f][r] + bv[f];
                float p = __shfl_xor(v, 1, 64);
                unsigned pk = (lane & 1) ? pack2(p, v) : pack2(v, p);
                int grow = rb + (wv << 4) + ((lane >> 4) << 2) + r;
                if (grow < nrows && ((lane & 1) == (f & 1))) {
                    Y[(size_t)grow * (COLS / 2) + f * 8 + ((lane & 15) >> 1)] = pk;
                }
            }
        }
    }
}

// ---------------- CSR build ----------------
__global__ __launch_bounds__(256) void hist_kernel(const int* __restrict__ dst,
                                                   int* __restrict__ counts) {
    int i = blockIdx.x * blockDim.x + threadIdx.x;
    const int stride = gridDim.x * blockDim.x;
    for (; i < N_EDGES / 4; i += stride) {
        int4 d = reinterpret_cast<const int4*>(dst)[i];
        atomicAdd(&counts[d.x], 1);
        atomicAdd(&counts[d.y], 1);
        atomicAdd(&counts[d.z], 1);
        atomicAdd(&counts[d.w], 1);
    }
}

// single-block scan, int4-widened
__global__ __launch_bounds__(1024) void scan_kernel(const int* __restrict__ counts,
                                                    int* __restrict__ rowptr) {
    __shared__ int wsum[16];
    const int tid = threadIdx.x;
    const int lane = tid & 63;
    const int w = tid >> 6;
    int offset = 0;
    if (tid == 0) rowptr[0] = 0;
    for (int base = 0; base < N_NODES; base += 4096) {
        int i = base + tid * 4;
        int4 v = make_int4(0, 0, 0, 0);
        if (i < N_NODES) v = *reinterpret_cast<const int4*>(counts + i);
        int p0 = v.x, p1 = p0 + v.y, p2 = p1 + v.z, p3 = p2 + v.w;
        int incl = p3;
#pragma unroll
        for (int d = 1; d < 64; d <<= 1) {
            int t = __shfl_up(incl, d, 64);
            if (lane >= d) incl += t;
        }
        if (lane == 63) wsum[w] = incl;
        __syncthreads();
        if (w == 0 && lane < 16) {
            int t = wsum[lane];
#pragma unroll
            for (int d = 1; d < 16; d <<= 1) {
                int u = __shfl_up(t, d, 64);
                if (lane >= d) t += u;
            }
            wsum[lane] = t;
        }
        __syncthreads();
        int woff = (w == 0) ? 0 : wsum[w - 1];
        int chunk_total = wsum[15];
        int tbase = offset + woff + incl - p3;
        if (i < N_NODES) {
            rowptr[i + 1] = tbase + p0;
            rowptr[i + 2] = tbase + p1;
            rowptr[i + 3] = tbase + p2;
            rowptr[i + 4] = tbase + p3;
        }
        offset += chunk_total;
        __syncthreads();
    }
}

// XCD-binned bucket
__global__ __launch_bounds__(256) void bucket_kernel(const int* __restrict__ src,
                                                     const int* __restrict__ dst,
                                                     const float* __restrict__ ew,
                                                     const int* __restrict__ rowptr,
                                                     int* __restrict__ fill,
                                                     int2* __restrict__ em) {
    const int myBin = blockIdx.x & (NBINS - 1);
    const int lo = myBin * BINW;
    const int hi = lo + BINW;
    int e = (blockIdx.x >> 3) * 256 + threadIdx.x;
    const int stride = (gridDim.x >> 3) * 256;
    for (; e < N_EDGES; e += stride) {
        int d = dst[e];
        if (d >= lo && d < hi) {
            int pos = atomicAdd(&fill[d], 1);
            em[rowptr[d] + pos] = make_int2(src[e], __float_as_int(ew[e]));
        }
    }
}

// ---- agg (bf16 H, 128 cols): half-wave per edge, uint2/lane (512B loads), bf16 B out ----
__global__ __launch_bounds__(256) void agg128b_kernel(const unsigned* __restrict__ Hb,
                                                      const int* __restrict__ rowptr,
                                                      const int2* __restrict__ em,
                                                      unsigned* __restrict__ Bb,
                                                      float* __restrict__ cs_part,
                                                      float* __restrict__ ss_part) {
    __shared__ int2 smeta[4][64];
    __shared__ float cs[4][128];
    __shared__ float ssw[4];
    const int wv = threadIdx.x >> 6;
    const int lane = threadIdx.x & 63;
    const int half = lane >> 5;  // which edge of the pair
    const int col2 = lane & 31;  // uint2 index within the 64-uint row
    const int node = blockIdx.x * 4 + wv;
    const int beg = rowptr[node];
    const int end = rowptr[node + 1];
    const int2* sm = smeta[wv];
    float a0 = 0.f, a1 = 0.f, a2 = 0.f, a3 = 0.f;

    for (int c = beg; c < end; c += 64) {
        smeta[wv][lane] = (c + lane < end) ? em[c + lane] : make_int2(0, 0);
        const int cnt = min(64, end - c);
        const int rounds = (cnt + 15) >> 4;  // 16 edges per round = 8 paired 512B loads
        for (int g = 0; g < rounds; ++g) {
            const int b = g * 16 + half;
            int2 m0 = sm[b + 0];
            int2 m1 = sm[b + 2];
            int2 m2 = sm[b + 4];
            int2 m3 = sm[b + 6];
            int2 m4 = sm[b + 8];
            int2 m5 = sm[b + 10];
            int2 m6 = sm[b + 12];
            int2 m7 = sm[b + 14];
            uint2 u0 = *reinterpret_cast<const uint2*>(Hb + (size_t)m0.x * 64 + col2 * 2);
            uint2 u1 = *reinterpret_cast<const uint2*>(Hb + (size_t)m1.x * 64 + col2 * 2);
            uint2 u2 = *reinterpret_cast<const uint2*>(Hb + (size_t)m2.x * 64 + col2 * 2);
            uint2 u3 = *reinterpret_cast<const uint2*>(Hb + (size_t)m3.x * 64 + col2 * 2);
            uint2 u4 = *reinterpret_cast<const uint2*>(Hb + (size_t)m4.x * 64 + col2 * 2);
            uint2 u5 = *reinterpret_cast<const uint2*>(Hb + (size_t)m5.x * 64 + col2 * 2);
            uint2 u6 = *reinterpret_cast<const uint2*>(Hb + (size_t)m6.x * 64 + col2 * 2);
            uint2 u7 = *reinterpret_cast<const uint2*>(Hb + (size_t)m7.x * 64 + col2 * 2);
            float w0 = __int_as_float(m0.y), w1 = __int_as_float(m1.y);
            float w2 = __int_as_float(m2.y), w3 = __int_as_float(m3.y);
            float w4 = __int_as_float(m4.y), w5 = __int_as_float(m5.y);
            float w6 = __int_as_float(m6.y), w7 = __int_as_float(m7.y);
            a0 += w0 * blo(u0.x); a1 += w0 * bhi(u0.x); a2 += w0 * blo(u0.y); a3 += w0 * bhi(u0.y);
            a0 += w1 * blo(u1.x); a1 += w1 * bhi(u1.x); a2 += w1 * blo(u1.y); a3 += w1 * bhi(u1.y);
            a0 += w2 * blo(u2.x); a1 += w2 * bhi(u2.x); a2 += w2 * blo(u2.y); a3 += w2 * bhi(u2.y);
            a0 += w3 * blo(u3.x); a1 += w3 * bhi(u3.x); a2 += w3 * blo(u3.y); a3 += w3 * bhi(u3.y);
            a0 += w4 * blo(u4.x); a1 += w4 * bhi(u4.x); a2 += w4 * blo(u4.y); a3 += w4 * bhi(u4.y);
            a0 += w5 * blo(u5.x); a1 += w5 * bhi(u5.x); a2 += w5 * blo(u5.y); a3 += w5 * bhi(u5.y);
            a0 += w6 * blo(u6.x); a1 += w6 * bhi(u6.x); a2 += w6 * blo(u6.y); a3 += w6 * bhi(u6.y);
            a0 += w7 * blo(u7.x); a1 += w7 * bhi(u7.x); a2 += w7 * blo(u7.y); a3 += w7 * bhi(u7.y);
        }
    }
    a0 += __shfl_xor(a0, 32, 64);
    a1 += __shfl_xor(a1, 32, 64);
    a2 += __shfl_xor(a2, 32, 64);
    a3 += __shfl_xor(a3, 32, 64);

    float sq = 0.f;
    if (lane < 32) {
        uint2 op;
        op.x = pack2(a0, a1);
        op.y = pack2(a2, a3);
        *reinterpret_cast<uint2*>(Bb + (size_t)node * 64 + col2 * 2) = op;
        cs[wv][col2 * 4 + 0] = a0;
        cs[wv][col2 * 4 + 1] = a1;
        cs[wv][col2 * 4 + 2] = a2;
        cs[wv][col2 * 4 + 3] = a3;
        sq = a0 * a0 + a1 * a1 + a2 * a2 + a3 * a3;
    }
#pragma unroll
    for (int off = 32; off; off >>= 1) sq += __shfl_down(sq, off, 64);
    if (lane == 0) ssw[wv] = sq;
    __syncthreads();
    const int rep = blockIdx.x & (NREP - 1);
    if (threadIdx.x < 128) {
        float s = cs[0][threadIdx.x] + cs[1][threadIdx.x] + cs[2][threadIdx.x] + cs[3][threadIdx.x];
        atomicAdd(&cs_part[rep * 128 + threadIdx.x], s);
    }
    if (threadIdx.x == 0) atomicAdd(&ss_part[rep], ssw[0] + ssw[1] + ssw[2] + ssw[3]);
}

// ---- agg (bf16 H, 64 cols): quarter-wave per edge, uint2/lane (512B loads), f32 out ----
__global__ __launch_bounds__(256) void agg64b_kernel(const unsigned* __restrict__ Hb,
                                                     const int* __restrict__ rowptr,
                                                     const int2* __restrict__ em,
                                                     float* __restrict__ out) {
    __shared__ int2 smeta[4][64];
    const int wv = threadIdx.x >> 6;
    const int lane = threadIdx.x & 63;
    const int q = lane >> 4;     // which edge of the quad
    const int col2 = lane & 15;  // uint2 index within the 32-uint row
    const int node = blockIdx.x * 4 + wv;
    const int beg = rowptr[node];
    const int end = rowptr[node + 1];
    const int2* sm = smeta[wv];
    float a0 = 0.f, a1 = 0.f, a2 = 0.f, a3 = 0.f;

    for (int c = beg; c < end; c += 64) {
        smeta[wv][lane] = (c + lane < end) ? em[c + lane] : make_int2(0, 0);
        const int cnt = min(64, end - c);
        const int rounds = (cnt + 31) >> 5;  // 32 edges per round = 8 quad 512B loads
        for (int g = 0; g < rounds; ++g) {
            const int b = g * 32 + q;
            int2 m0 = sm[b + 0];
            int2 m1 = sm[b + 4];
            int2 m2 = sm[b + 8];
            int2 m3 = sm[b + 12];
            int2 m4 = sm[b + 16];
            int2 m5 = sm[b + 20];
            int2 m6 = sm[b + 24];
            int2 m7 = sm[b + 28];
            uint2 u0 = *reinterpret_cast<const uint2*>(Hb + (size_t)m0.x * 32 + col2 * 2);
            uint2 u1 = *reinterpret_cast<const uint2*>(Hb + (size_t)m1.x * 32 + col2 * 2);
            uint2 u2 = *reinterpret_cast<const uint2*>(Hb + (size_t)m2.x * 32 + col2 * 2);
            uint2 u3 = *reinterpret_cast<const uint2*>(Hb + (size_t)m3.x * 32 + col2 * 2);
            uint2 u4 = *reinterpret_cast<const uint2*>(Hb + (size_t)m4.x * 32 + col2 * 2);
            uint2 u5 = *reinterpret_cast<const uint2*>(Hb + (size_t)m5.x * 32 + col2 * 2);
            uint2 u6 = *reinterpret_cast<const uint2*>(Hb + (size_t)m6.x * 32 + col2 * 2);
            uint2 u7 = *reinterpret_cast<const uint2*>(Hb + (size_t)m7.x * 32 + col2 * 2);
            float w0 = __int_as_float(m0.y), w1 = __int_as_float(m1.y);
            float w2 = __int_as_float(m2.y), w3 = __int_as_float(m3.y);
            float w4 = __int_as_float(m4.y), w5 = __int_as_float(m5.y);
            float w6 = __int_as_float(m6.y), w7 = __int_as_float(m7.y);
            a0 += w0 * blo(u0.x); a1 += w0 * bhi(u0.x); a2 += w0 * blo(u0.y); a3 += w0 * bhi(u0.y);
            a0 += w1 * blo(u1.x); a1 += w1 * bhi(u1.x); a2 += w1 * blo(u1.y); a3 += w1 * bhi(u1.y);
            a0 += w2 * blo(u2.x); a1 += w2 * bhi(u2.x); a2 += w2 * blo(u2.y); a3 += w2 * bhi(u2.y);
            a0 += w3 * blo(u3.x); a1 += w3 * bhi(u3.x); a2 += w3 * blo(u3.y); a3 += w3 * bhi(u3.y);
            a0 += w4 * blo(u4.x); a1 += w4 * bhi(u4.x); a2 += w4 * blo(u4.y); a3 += w4 * bhi(u4.y);
            a0 += w5 * blo(u5.x); a1 += w5 * bhi(u5.x); a2 += w5 * blo(u5.y); a3 += w5 * bhi(u5.y);
            a0 += w6 * blo(u6.x); a1 += w6 * bhi(u6.x); a2 += w6 * blo(u6.y); a3 += w6 * bhi(u6.y);
            a0 += w7 * blo(u7.x); a1 += w7 * bhi(u7.x); a2 += w7 * blo(u7.y); a3 += w7 * bhi(u7.y);
        }
    }
    a0 += __shfl_xor(a0, 16, 64); a0 += __shfl_xor(a0, 32, 64);
    a1 += __shfl_xor(a1, 16, 64); a1 += __shfl_xor(a1, 32, 64);
    a2 += __shfl_xor(a2, 16, 64); a2 += __shfl_xor(a2, 32, 64);
    a3 += __shfl_xor(a3, 16, 64); a3 += __shfl_xor(a3, 32, 64);
    if (lane < 16) {
        *reinterpret_cast<float4*>(out + (size_t)node * DOUT + col2 * 4) =
            make_float4(a0, a1, a2, a3);
    }
}

// ---------------- finalize: reduce replicas -> mu, inv ----------------
__global__ void finalize_stats(const float* __restrict__ cs_part,
                               const float* __restrict__ ss_part, float* __restrict__ mu,
                               float* __restrict__ inv) {
    const int t = threadIdx.x;  // 128 threads
    float m = 0.f;
    for (int r = 0; r < NREP; ++r) m += cs_part[r * 128 + t];
    float mean = m / (float)N_NODES;
    mu[t] = mean;
    float v = mean * mean;
    __shared__ float partl[2];
    __shared__ float sstot;
#pragma unroll
    for (int off = 32; off; off >>= 1) v += __shfl_down(v, off, 64);
    if ((t & 63) == 0) partl[t >> 6] = v;
    float ss = (t < NREP) ? ss_part[t] : 0.f;
#pragma unroll
    for (int off = 32; off; off >>= 1) ss += __shfl_down(ss, off, 64);
    if (t == 0) sstot = ss;
    __syncthreads();
    if (t == 0) {
        float musq = partl[0] + partl[1];
        float s = (sstot - (float)N_NODES * musq) / (float)N_NODES;
        inv[0] = rsqrtf(EPS + s);
    }
}

extern "C" void kernel_launch(void* const* d_in, const int* in_sizes, int n_in,
                              void* d_out, int out_size, void* d_ws, size_t ws_size,
                              hipStream_t stream) {
    const float* x = (const float*)d_in[0];
    const int* edge_index = (const int*)d_in[1];
    const float* ew = (const float*)d_in[2];
    const float* W0 = (const float*)d_in[3];
    const float* b0 = (const float*)d_in[4];
    const float* W1 = (const float*)d_in[5];
    const float* b1 = (const float*)d_in[6];
    const float* Wout = (const float*)d_in[7];
    const float* bout = (const float*)d_in[8];

    const int* src = edge_index;
    const int* dst = edge_index + N_EDGES;
    float* out = (float*)d_out;

    // workspace layout (all bf16-packed node matrices are uint[N][64])
    unsigned* base = (unsigned*)d_ws;
    unsigned* Hb = base;                             // uint[N][64]; out-layer uses uint[N][32]
    unsigned* B1b = base + (size_t)N_NODES * 64;     // uint[N][64] bf16 B1
    unsigned* B2b = B1b + (size_t)N_NODES * 64;      // uint[N][64] bf16 B2
    int2* em = (int2*)(B2b + (size_t)N_NODES * 64);  // E int2
    int* counts = (int*)(em + N_EDGES);              // N
    int* fill = counts + N_NODES;                    // N
    int* rowptr = fill + N_NODES;                    // N+1
    size_t soff = (size_t)(rowptr + N_NODES + 1 - (int*)base);
    soff = (soff + 3) & ~(size_t)3;
    float* stats = (float*)base + soff;
    float* cs_part1 = stats;                  // NREP*128
    float* ss_part1 = cs_part1 + NREP * 128;  // NREP
    float* cs_part2 = ss_part1 + NREP;        // NREP*128
    float* ss_part2 = cs_part2 + NREP * 128;  // NREP
    float* mu1 = ss_part2 + NREP;             // 128
    float* inv1 = mu1 + 128;                  // 1 (+3 pad)
    float* mu2 = inv1 + 4;                    // 128
    float* inv2 = mu2 + 128;                  // 1

    const int gemm_grid = (N_NODES + 127) / 128;  // 782
    const int agg_grid = N_NODES / 4;             // 25000 exact

    // zero init
    hipMemsetAsync(counts, 0, (size_t)2 * N_NODES * sizeof(int), stream);  // counts + fill
    hipMemsetAsync(stats, 0, (size_t)2 * (NREP * 128 + NREP) * sizeof(float), stream);

    // CSR build (dst-ordered)
    hist_kernel<<<1024, 256, 0, stream>>>(dst, counts);
    scan_kernel<<<1, 1024, 0, stream>>>(counts, rowptr);
    bucket_kernel<<<2048, 256, 0, stream>>>(src, dst, ew, rowptr, fill, em);

    // Layer 1
    gemm_mfma<128, 0><<<gemm_grid, 256, 0, stream>>>(
        x, nullptr, nullptr, nullptr, nullptr, nullptr, W0, b0, Hb, N_NODES);
    agg128b_kernel<<<agg_grid, 256, 0, stream>>>(Hb, rowptr, em, B1b, cs_part1, ss_part1);
    finalize_stats<<<1, 128, 0, stream>>>(cs_part1, ss_part1, mu1, inv1);

    // Layer 2
    gemm_mfma<128, 1><<<gemm_grid, 256, 0, stream>>>(
        B1b, mu1, inv1, nullptr, nullptr, nullptr, W1, b1, Hb, N_NODES);
    agg128b_kernel<<<agg_grid, 256, 0, stream>>>(Hb, rowptr, em, B2b, cs_part2, ss_part2);
    finalize_stats<<<1, 128, 0, stream>>>(cs_part2, ss_part2, mu2, inv2);

    // Output layer: HOUT(bf16) = (relu(pn2(B2))+relu(pn1(B1)))@Wout+bout; out = gather
    gemm_mfma<64, 2><<<gemm_grid, 256, 0, stream>>>(
        B2b, mu2, inv2, B1b, mu1, inv1, Wout, bout, Hb, N_NODES);
    agg64b_kernel<<<agg_grid, 256, 0, stream>>>(Hb, rowptr, em, out);
}